// Round 4
// baseline (568.570 us; speedup 1.0000x reference)
//
#include <hip/hip_runtime.h>
#include <stdint.h>

#define NN 4096
#define NGG 4096
#define NUU 8192

// ---- spatial grid params (exact-coverage domain for N(0,1) data) ----
#define GD 32
#define GH 0.34375f          /* 11/32, exact in binary */
#define GORG -5.5f           /* grid covers [-5.5, 5.5] */
#define GINVH 2.90909090909f /* 1/GH; build & query use identical cellc() */

__device__ __forceinline__ int cellc(float v) {
  int c = (int)((v - GORG) * GINVH);
  return c < 0 ? 0 : (c > 31 ? 31 : c);
}

// ---------------- block-wide sum (blockDim.x == 256) -------------------
__device__ __forceinline__ float block_sum_256(float v, float* sbuf) {
#pragma unroll
  for (int o = 32; o > 0; o >>= 1) v += __shfl_down(v, o, 64);
  int lane = threadIdx.x & 63;
  int w = threadIdx.x >> 6;
  if (lane == 0) sbuf[w] = v;
  __syncthreads();
  float r = 0.f;
  if (threadIdx.x == 0) r = sbuf[0] + sbuf[1] + sbuf[2] + sbuf[3];
  __syncthreads();
  return r;
}

// ---- point decode shared by count/scatter: 98304 points total --------
// pid -> (combo cb = b*4+s, local index i, xyz).  sets: 0=gt 1=up 2=off 3=pts
__device__ __forceinline__ void decode_point(int pid, const float* gt,
                                             const float* up, const float* off,
                                             const float* pts, int& cb, int& i,
                                             float& x, float& y, float& z) {
  int b = pid / 24576;
  int rem = pid - b * 24576;
  int s;
  const float* p;
  if (rem < 4096) { s = 0; i = rem; p = gt + (size_t)(b * NGG + i) * 6; }
  else if (rem < 12288) { s = 1; i = rem - 4096; p = up + (size_t)(b * NUU + i) * 3; }
  else if (rem < 20480) { s = 2; i = rem - 12288; p = off + (size_t)(b * NUU + i) * 3; }
  else { s = 3; i = rem - 20480; p = pts + (size_t)(b * NN + i) * 3; }
  cb = b * 4 + s;
  x = p[0]; y = p[1]; z = p[2];
}

// sorted-array base offset for combo cb (in float4 elements)
__device__ __forceinline__ int combo_base(int cb) {
  int b = cb >> 2, s = cb & 3;
  int offs = (s == 0) ? 0 : (s == 1) ? 4096 : (s == 2) ? 12288 : 20480;
  return b * 24576 + offs;
}

// ---------------- grid build ------------------------------------------
__global__ __launch_bounds__(256) void k_count(const float* __restrict__ gt,
                                               const float* __restrict__ up,
                                               const float* __restrict__ off,
                                               const float* __restrict__ pts,
                                               unsigned* __restrict__ counts) {
  int pid = blockIdx.x * 256 + threadIdx.x;   // grid 384 -> exactly 98304
  int cb, i; float x, y, z;
  decode_point(pid, gt, up, off, pts, cb, i, x, y, z);
  int cell = (cellc(z) * GD + cellc(y)) * GD + cellc(x);
  atomicAdd(&counts[cb * 32768 + cell], 1u);
}

// one block per combo: exclusive prefix over 32768 cells
__global__ __launch_bounds__(256) void k_prefix(const unsigned* __restrict__ counts,
                                                unsigned* __restrict__ starts,
                                                unsigned* __restrict__ cursor) {
  __shared__ unsigned ssum[256];
  int cb = blockIdx.x, t = threadIdx.x;
  const unsigned* c = counts + cb * 32768;
  unsigned* st = starts + cb * 32768;
  unsigned* cu = cursor + cb * 32768;
  int base = t * 128;
  unsigned s = 0;
  for (int i = 0; i < 128; ++i) s += c[base + i];
  ssum[t] = s;
  __syncthreads();
  for (int off = 1; off < 256; off <<= 1) {
    unsigned v = 0;
    if (t >= off) v = ssum[t - off];
    __syncthreads();
    if (t >= off) ssum[t] += v;
    __syncthreads();
  }
  unsigned run = (t == 0) ? 0u : ssum[t - 1];
  for (int i = 0; i < 128; ++i) {
    st[base + i] = run;
    cu[base + i] = run;
    run += c[base + i];
  }
}

__global__ __launch_bounds__(256) void k_scatter(const float* __restrict__ gt,
                                                 const float* __restrict__ up,
                                                 const float* __restrict__ off,
                                                 const float* __restrict__ pts,
                                                 unsigned* __restrict__ cursor,
                                                 float4* __restrict__ sorted) {
  int pid = blockIdx.x * 256 + threadIdx.x;
  int cb, i; float x, y, z;
  decode_point(pid, gt, up, off, pts, cb, i, x, y, z);
  int cell = (cellc(z) * GD + cellc(y)) * GD + cellc(x);
  unsigned pos = atomicAdd(&cursor[cb * 32768 + cell], 1u);
  sorted[combo_base(cb) + pos] = make_float4(x, y, z, __int_as_float(i));
}

// ---------------- exact grid NN search --------------------------------
// MODE 0: min distance (float). MODE 1: min (dist,idx) u64 key. MODE 2: 6-NN idx.
// Bound: cells at Chebyshev ring r are >= (r-1)*H + moff away (moff = min
// per-axis distance of p to its own cell's faces). Plus per-cell AABB prune.
template <int MODE>
__device__ __forceinline__ void grid_search(float px, float py, float pz,
                                            const unsigned* __restrict__ stc,
                                            const unsigned* __restrict__ cnc,
                                            const float4* __restrict__ srt,
                                            float* out_d,
                                            unsigned long long* out_key,
                                            int* out_idx6) {
  const unsigned long long KINIT = 0x7F800000ULL << 32;  // +inf distance bits
  int cx = cellc(px), cy = cellc(py), cz = cellc(pz);
  float ox = px - (GORG + cx * GH);
  float oy = py - (GORG + cy * GH);
  float oz = pz - (GORG + cz * GH);
  float moff = fminf(fminf(fminf(ox, GH - ox), fminf(oy, GH - oy)),
                     fminf(oz, GH - oz));
  float bestd = 3.4e38f;
  unsigned long long bk = KINIT;
  unsigned long long k0 = KINIT, k1 = KINIT, k2 = KINIT, k3 = KINIT,
                     k4 = KINIT, k5 = KINIT;
  for (int r = 0; r < 32; ++r) {
    if (r >= 1) {
      float t = (float)(r - 1) * GH + moff;
      if (t > 0.f && t * t >= bestd) break;
    }
    for (int dz = -r; dz <= r; ++dz) {
      int z = cz + dz;
      if ((unsigned)z > 31u) continue;
      bool zf = (dz == -r) | (dz == r);
      float lz = GORG + z * GH;
      float dzm = fmaxf(0.f, fmaxf(lz - pz, pz - (lz + GH)));
      float dz2 = dzm * dzm;
      if (dz2 >= bestd) continue;
      for (int dy = -r; dy <= r; ++dy) {
        int y = cy + dy;
        if ((unsigned)y > 31u) continue;
        bool yf = (dy == -r) | (dy == r);
        float ly = GORG + y * GH;
        float dym = fmaxf(0.f, fmaxf(ly - py, py - (ly + GH)));
        float dyz2 = fmaf(dym, dym, dz2);
        if (dyz2 >= bestd) continue;
        int step = (zf | yf) ? 1 : 2 * r;
        for (int dx = -r; dx <= r; dx += step) {
          int x = cx + dx;
          if ((unsigned)x > 31u) continue;
          float lx = GORG + x * GH;
          float dxm = fmaxf(0.f, fmaxf(lx - px, px - (lx + GH)));
          float cmin = fmaf(dxm, dxm, dyz2);
          if (cmin >= bestd) continue;
          int cell = (z * GD + y) * GD + x;
          unsigned s0 = stc[cell];
          unsigned n = cnc[cell];
          for (unsigned j = 0; j < n; ++j) {
            float4 c = srt[s0 + j];
            float ax = px - c.x, ay = py - c.y, az = pz - c.z;
            float d = fmaf(ax, ax, fmaf(ay, ay, az * az));
            if (MODE == 0) {
              bestd = fminf(bestd, d);
            } else if (MODE == 1) {
              unsigned long long key =
                  ((unsigned long long)__float_as_uint(d) << 32) |
                  (unsigned)__float_as_int(c.w);
              bk = key < bk ? key : bk;
              bestd = fminf(bestd, d);
            } else {
              if (d < bestd) {   // bestd tracks k5's distance
                unsigned long long cand =
                    ((unsigned long long)__float_as_uint(d) << 32) |
                    (unsigned)__float_as_int(c.w);
                unsigned long long mn;
                mn = cand < k0 ? cand : k0; cand = cand < k0 ? k0 : cand; k0 = mn;
                mn = cand < k1 ? cand : k1; cand = cand < k1 ? k1 : cand; k1 = mn;
                mn = cand < k2 ? cand : k2; cand = cand < k2 ? k2 : cand; k2 = mn;
                mn = cand < k3 ? cand : k3; cand = cand < k3 ? k3 : cand; k3 = mn;
                mn = cand < k4 ? cand : k4; cand = cand < k4 ? k4 : cand; k4 = mn;
                mn = cand < k5 ? cand : k5;                               k5 = mn;
                bestd = __uint_as_float((unsigned)(k5 >> 32));
              }
            }
          }
        }
      }
    }
  }
  if (MODE == 0) *out_d = bestd;
  if (MODE == 1) *out_key = bk;
  if (MODE == 2) {
    out_idx6[0] = (int)(k0 & 0xffffffffULL);
    out_idx6[1] = (int)(k1 & 0xffffffffULL);
    out_idx6[2] = (int)(k2 & 0xffffffffULL);
    out_idx6[3] = (int)(k3 & 0xffffffffULL);
    out_idx6[4] = (int)(k4 & 0xffffffffULL);
    out_idx6[5] = (int)(k5 & 0xffffffffULL);
  }
}

// ---------------- all NN queries in one dispatch ----------------------
// blocks [0,64): knn6 pts->pts   [64,128): argmin pts->gt
// blocks [128,384): cham rows up/off->gt   [384,448): cham cols gt->off,up
__global__ __launch_bounds__(256) void k_queries(
    const unsigned* __restrict__ starts, const unsigned* __restrict__ counts,
    const float4* __restrict__ sorted, unsigned long long* __restrict__ keys,
    float* __restrict__ rowminf, float* __restrict__ colminf,
    int* __restrict__ knn_idx) {
  int blk = blockIdx.x, tid = threadIdx.x;
  if (blk < 64) {
    int qid = blk * 256 + tid;           // [0,16384)
    int b = qid >> 12, i = qid & 4095;
    const float4* srt = sorted + b * 24576 + 20480;  // pts sorted
    float4 p = srt[i];
    int orig = __float_as_int(p.w);
    int cb = b * 4 + 3;
    int idx6[6];
    grid_search<2>(p.x, p.y, p.z, starts + cb * 32768, counts + cb * 32768,
                   srt, nullptr, nullptr, idx6);
    int* o = knn_idx + (size_t)(b * 4096 + orig) * 6;
#pragma unroll
    for (int k = 0; k < 6; ++k) o[k] = idx6[k];
  } else if (blk < 128) {
    int qid = (blk - 64) * 256 + tid;    // [0,16384)
    int b = qid >> 12, i = qid & 4095;
    const float4* srtq = sorted + b * 24576 + 20480;  // pts sorted
    float4 p = srtq[i];
    int orig = __float_as_int(p.w);
    int cb = b * 4 + 0;                  // gt grid
    unsigned long long bk;
    grid_search<1>(p.x, p.y, p.z, starts + cb * 32768, counts + cb * 32768,
                   sorted + b * 24576, nullptr, &bk, nullptr);
    keys[b * 4096 + orig] = bk;
  } else if (blk < 384) {
    int qid = (blk - 128) * 256 + tid;   // [0,65536)
    int which = qid >> 15;               // 0=off, 1=up
    int r = qid & 32767;
    int b = r >> 13, i = r & 8191;
    const float4* srtq = sorted + b * 24576 + (which ? 4096 : 12288);
    float4 p = srtq[i];
    int orig = __float_as_int(p.w);
    int cb = b * 4 + 0;                  // gt grid
    float d;
    grid_search<0>(p.x, p.y, p.z, starts + cb * 32768, counts + cb * 32768,
                   sorted + b * 24576, &d, nullptr, nullptr);
    rowminf[which * 32768 + b * 8192 + orig] = d;
  } else {
    int qid = (blk - 384) * 256 + tid;   // [0,16384)
    int b = qid >> 12, i = qid & 4095;
    const float4* srtq = sorted + b * 24576;  // gt sorted
    float4 p = srtq[i];
    int orig = __float_as_int(p.w);
    int cbo = b * 4 + 2, cbu = b * 4 + 1;
    float doff, dup;
    grid_search<0>(p.x, p.y, p.z, starts + cbo * 32768, counts + cbo * 32768,
                   sorted + b * 24576 + 12288, &doff, nullptr, nullptr);
    grid_search<0>(p.x, p.y, p.z, starts + cbu * 32768, counts + cbu * 32768,
                   sorted + b * 24576 + 4096, &dup, nullptr, nullptr);
    colminf[b * 4096 + orig] = doff;
    colminf[16384 + b * 4096 + orig] = dup;
  }
}

// ------------- fused: postgather (blocks 0..63) + reduce mins (64..447) -
__global__ __launch_bounds__(256) void k_post(
    const float* __restrict__ ori_pre, const float* __restrict__ nor_pre,
    const float* __restrict__ gt, const unsigned long long* __restrict__ keys,
    const float* __restrict__ rowminf, const float* __restrict__ colminf,
    float* __restrict__ nor_gt, float* __restrict__ ori_pro, float* __restrict__ acc) {
  __shared__ float sb1[4], sb2[4];
  int blk = blockIdx.x;
  if (blk < 64) {
    int q = blk * 256 + threadIdx.x;
    int b = q >> 12;
    float ox = ori_pre[q * 3 + 0], oy = ori_pre[q * 3 + 1], oz = ori_pre[q * 3 + 2];
    float n1 = sqrtf(fmaf(ox, ox, fmaf(oy, oy, oz * oz)) + 1e-8f) + 1e-10f;
    ox /= n1; oy /= n1; oz /= n1;
    float px = nor_pre[q * 3 + 0], py = nor_pre[q * 3 + 1], pz = nor_pre[q * 3 + 2];
    float n2 = sqrtf(fmaf(px, px, fmaf(py, py, pz * pz)) + 1e-8f) + 1e-10f;
    px /= n2; py /= n2; pz /= n2;
    unsigned idx = (unsigned)(keys[q] & 0xffffffffULL);
    const float* g = gt + (size_t)b * NGG * 6 + (size_t)idx * 6 + 3;
    float gx = g[0], gy = g[1], gz = g[2];
    float dn = fmaf(gx, ox, fmaf(gy, oy, gz * oz));
    float vx = ox - gx * dn, vy = oy - gy * dn, vz = oz - gz * dn;
    float n3 = sqrtf(fmaf(vx, vx, fmaf(vy, vy, vz * vz)) + 1e-8f) + 1e-10f;
    vx /= n3; vy /= n3; vz /= n3;
    nor_gt[q * 3 + 0] = gx; nor_gt[q * 3 + 1] = gy; nor_gt[q * 3 + 2] = gz;
    ori_pro[q * 3 + 0] = vx; ori_pro[q * 3 + 1] = vy; ori_pro[q * 3 + 2] = vz;
    float na = fmaxf(sqrtf(fmaf(gx, gx, fmaf(gy, gy, gz * gz))), 1e-8f);
    float nb = fmaxf(sqrtf(fmaf(px, px, fmaf(py, py, pz * pz))), 1e-8f);
    float cs = fmaf(gx, px, fmaf(gy, py, gz * pz)) / (na * nb);
    float t_nor = 1.f - fabsf(cs);
    float t_ori = fabsf(dn);
    float s1 = block_sum_256(t_nor, sb1);
    float s2 = block_sum_256(t_ori, sb2);
    if (threadIdx.x == 0) {
      atomicAdd(&acc[1], s1);
      atomicAdd(&acc[2], s2);
    }
  } else {
    int rblk = blk - 64;   // [0,384)
    float v;
    int slot;
    if (rblk < 256) {
      int i = rblk * 256 + threadIdx.x;
      v = rowminf[i];
      slot = (i >> 15) ? 5 : 3;   // 0=offset rows -> acc3, 1=up rows -> acc5
    } else {
      int i = (rblk - 256) * 256 + threadIdx.x;
      v = colminf[i];
      slot = (i >> 14) ? 6 : 4;   // 0=offset cols -> acc4, 1=up cols -> acc6
    }
    float s = block_sum_256(v, sb1);
    if (threadIdx.x == 0) atomicAdd(&acc[slot], s);
  }
}

// ------------- loss_smooth epilogue: one thread per query -------------
__global__ __launch_bounds__(256) void k_smooth(const int* __restrict__ knn_idx,
                                                const float* __restrict__ nor_gt,
                                                const float* __restrict__ ori_pro,
                                                float* __restrict__ acc) {
  __shared__ float sbuf[4];
  int q = blockIdx.x * 256 + threadIdx.x;
  int b = q >> 12;
  float ngx = nor_gt[q * 3 + 0], ngy = nor_gt[q * 3 + 1], ngz = nor_gt[q * 3 + 2];
  float box = ori_pro[q * 3 + 0], boy = ori_pro[q * 3 + 1], boz = ori_pro[q * 3 + 2];
  float rx = boy * ngz - boz * ngy;
  float ry = boz * ngx - box * ngz;
  float rz = box * ngy - boy * ngx;
  float nbo = fmaxf(sqrtf(fmaf(box, box, fmaf(boy, boy, boz * boz))), 1e-8f);
  float nrot = fmaxf(sqrtf(fmaf(rx, rx, fmaf(ry, ry, rz * rz))), 1e-8f);
  const int* nb6 = knn_idx + (size_t)q * 6;
  float sum = 0.f;
#pragma unroll
  for (int k = 0; k < 6; ++k) {
    int id = nb6[k];
    const float* gn = &nor_gt[(size_t)(b * 4096 + id) * 3];
    const float* go = &ori_pro[(size_t)(b * 4096 + id) * 3];
    float gnx = gn[0], gny = gn[1], gnz = gn[2];
    float gox = go[0], goy = go[1], goz = go[2];
    float nd = fmaf(gnx, ngx, fmaf(gny, ngy, gnz * ngz));
    float wv = (expf(-nd / 0.3f) * 10.f + 1.f) < 4.f ? 1.f : 5.f;
    float ngo = fmaxf(sqrtf(fmaf(gox, gox, fmaf(goy, goy, goz * goz))), 1e-8f);
    float c0 = fmaf(gox, box, fmaf(goy, boy, goz * boz)) / (ngo * nbo);
    float c1 = fmaf(gox, rx, fmaf(goy, ry, goz * rz)) / (ngo * nrot);
    float cosv = fminf(1.f - fabsf(c0), 1.f - fabsf(c1));
    sum += wv * cosv;
  }
  float s = block_sum_256(sum, sbuf);
  if (threadIdx.x == 0) atomicAdd(&acc[0], s);
}

// ------------- combine to the 7 outputs --------------------------------
__global__ void k_finalize(const float* __restrict__ acc, float* __restrict__ out) {
  if (threadIdx.x == 0 && blockIdx.x == 0) {
    float loss_smooth = acc[0] / 98304.f;            // B*N*K
    float loss_nor = acc[1] / 16384.f;               // B*N
    float loss_nor_ori = acc[2] / 16384.f;
    float lco = acc[3] / 32768.f + acc[4] / 16384.f; // B*NU rows + B*NG cols
    float lc = acc[5] / 32768.f + acc[6] / 16384.f;
    float loss_cd = lc + 0.4f * lco;
    float loss = loss_smooth + loss_nor + 0.1f * loss_nor_ori + 200.f * loss_cd;
    out[0] = loss;
    out[1] = loss_smooth;
    out[2] = loss_nor;
    out[3] = lco;
    out[4] = loss_nor_ori;
    out[5] = lc;
    out[6] = lc;
  }
}

extern "C" void kernel_launch(void* const* d_in, const int* in_sizes, int n_in,
                              void* d_out, int out_size, void* d_ws, size_t ws_size,
                              hipStream_t stream) {
  (void)in_sizes; (void)n_in; (void)out_size; (void)ws_size;
  const float* ori_pre = (const float*)d_in[0];
  const float* nor_pre = (const float*)d_in[1];
  const float* xyz_up = (const float*)d_in[2];
  const float* xyz_off = (const float*)d_in[3];
  const float* pts = (const float*)d_in[4];
  const float* gt = (const float*)d_in[5];
  float* out = (float*)d_out;
  char* ws = (char*)d_ws;

  float* acc = (float*)(ws + 0);                              // 64 B
  unsigned long long* keys = (unsigned long long*)(ws + 512); // 16384 u64
  float* rowminf = (float*)(ws + 131584);                     // 65536 f32
  float* colminf = (float*)(ws + 393728);                     // 32768 f32
  float* nor_gt = (float*)(ws + 524800);                      // 49152 f32
  float* ori_pro = (float*)(ws + 721408);                     // 49152 f32
  int* knn_idx = (int*)(ws + 918016);                         // 98304 i32
  unsigned* counts = (unsigned*)(ws + 1311232);               // 16*32768 u32
  unsigned* starts = (unsigned*)(ws + 3408384);               // 16*32768 u32
  unsigned* cursor = (unsigned*)(ws + 5505536);               // 16*32768 u32
  float4* sorted = (float4*)(ws + 7602688);                   // 98304 float4

  hipMemsetAsync(acc, 0, 64, stream);
  hipMemsetAsync(counts, 0, 16 * 32768 * sizeof(unsigned), stream);

  k_count<<<384, 256, 0, stream>>>(gt, xyz_up, xyz_off, pts, counts);
  k_prefix<<<16, 256, 0, stream>>>(counts, starts, cursor);
  k_scatter<<<384, 256, 0, stream>>>(gt, xyz_up, xyz_off, pts, cursor, sorted);
  k_queries<<<448, 256, 0, stream>>>(starts, counts, sorted, keys, rowminf,
                                     colminf, knn_idx);
  k_post<<<448, 256, 0, stream>>>(ori_pre, nor_pre, gt, keys, rowminf, colminf,
                                  nor_gt, ori_pro, acc);
  k_smooth<<<64, 256, 0, stream>>>(knn_idx, nor_gt, ori_pro, acc);
  k_finalize<<<1, 64, 0, stream>>>(acc, out);
}

// Round 6
// 281.171 us; speedup vs baseline: 2.0222x; 2.0222x over previous
//
#include <hip/hip_runtime.h>
#include <stdint.h>

#define NN 4096
#define NGG 4096
#define NUU 8192

// monotone float->uint mapping (order-preserving incl. negatives)
__device__ __forceinline__ unsigned fkey32(float f) {
  unsigned u = __float_as_uint(f);
  return u ^ (((int)u >> 31) | 0x80000000u);
}
__device__ __forceinline__ float unfkey32(unsigned k) {
  unsigned m = (k & 0x80000000u) ? 0x80000000u : 0xFFFFFFFFu;
  return __uint_as_float(k ^ m);
}

// ---------------- block-wide sum (blockDim.x == 256) -------------------
__device__ __forceinline__ float block_sum_256(float v, float* sbuf) {
#pragma unroll
  for (int o = 32; o > 0; o >>= 1) v += __shfl_down(v, o, 64);
  int lane = threadIdx.x & 63;
  int w = threadIdx.x >> 6;
  if (lane == 0) sbuf[w] = v;
  __syncthreads();
  float r = 0.f;
  if (threadIdx.x == 0) r = sbuf[0] + sbuf[1] + sbuf[2] + sbuf[3];
  __syncthreads();
  return r;
}

// ---------------- block-wide sum (blockDim.x == 512) -------------------
__device__ __forceinline__ float block_sum_512(float v, float* sbuf) {
#pragma unroll
  for (int o = 32; o > 0; o >>= 1) v += __shfl_down(v, o, 64);
  int lane = threadIdx.x & 63;
  int w = threadIdx.x >> 6;
  if (lane == 0) sbuf[w] = v;
  __syncthreads();
  float r = 0.f;
  if (threadIdx.x == 0)
    r = sbuf[0] + sbuf[1] + sbuf[2] + sbuf[3] + sbuf[4] + sbuf[5] + sbuf[6] + sbuf[7];
  __syncthreads();
  return r;
}

// sorted 6-element insert of (d, ci), ascending by d (ties keep earlier idx:
// strict < means equal-d later candidate goes after — and candidate order is
// ascending index, matching jax stable top_k)
__device__ __forceinline__ void ins6(float d, int ci,
                                     float& d0, float& d1, float& d2,
                                     float& d3, float& d4, float& d5,
                                     int& i0, int& i1, int& i2,
                                     int& i3, int& i4, int& i5) {
  bool cc; float nd; int ni;
  cc = d < d0; nd = cc ? d : d0; d = cc ? d0 : d; ni = cc ? ci : i0; ci = cc ? i0 : ci; d0 = nd; i0 = ni;
  cc = d < d1; nd = cc ? d : d1; d = cc ? d1 : d; ni = cc ? ci : i1; ci = cc ? i1 : ci; d1 = nd; i1 = ni;
  cc = d < d2; nd = cc ? d : d2; d = cc ? d2 : d; ni = cc ? ci : i2; ci = cc ? i2 : ci; d2 = nd; i2 = ni;
  cc = d < d3; nd = cc ? d : d3; d = cc ? d3 : d; ni = cc ? ci : i3; ci = cc ? i3 : ci; d3 = nd; i3 = ni;
  cc = d < d4; nd = cc ? d : d4; d = cc ? d4 : d; ni = cc ? ci : i4; ci = cc ? i4 : ci; d4 = nd; i4 = ni;
  cc = d < d5; nd = cc ? d : d5;                  ni = cc ? ci : i5;                    d5 = nd; i5 = ni;
}

// ---------------- fused scan: cham rows + cham cols + argmin -----------
// Q=8 queries/thread: one ds_read_b128 per candidate serves 8 pair-evals.
// blocks [0,256): cham_row; [256,512): cham_col; [512,576): argmin
__global__ __launch_bounds__(256) void k_scan(const float* __restrict__ pts,
                                              const float* __restrict__ gt,
                                              const float* __restrict__ up,
                                              const float* __restrict__ off,
                                              unsigned long long* __restrict__ keys,
                                              unsigned* __restrict__ rowmin,
                                              unsigned* __restrict__ colmin) {
  __shared__ float4 sc[512];   // 8 KB
  int blk = blockIdx.x;
  int tid = threadIdx.x;

  float ax[8], ay[8], az[8], qq[8], bst[8];

  if (blk < 512) {
    if (blk < 256) {
      // ---- cham_row: 65536 queries (off,up), candidates = gt segs ----
      int qb = blk >> 3;     // [0,32)
      int seg = blk & 7;     // [0,8)
      int which = qb >> 4;
      int b = (qb >> 2) & 3;
      int chunk = qb & 3;
      // stage gt seg (512 pts, stride-6 source)
      const float* gtb = gt + (size_t)b * NGG * 6 + (size_t)seg * 512 * 6;
      int i0 = tid * 2;
      const float4* g4 = (const float4*)(gtb + (size_t)i0 * 6);
      float4 u0 = g4[0], u1 = g4[1], u2 = g4[2];
      sc[i0] = make_float4(u0.x, u0.y, u0.z,
                           fmaf(u0.x, u0.x, fmaf(u0.y, u0.y, u0.z * u0.z)));
      sc[i0 + 1] = make_float4(u1.z, u1.w, u2.x,
                               fmaf(u1.z, u1.z, fmaf(u1.w, u1.w, u2.x * u2.x)));
      const float* qsrc = (which ? up : off) + (size_t)(b * NUU + chunk * 2048) * 3;
#pragma unroll
      for (int k = 0; k < 8; ++k) {
        const float* p = qsrc + (size_t)(tid + k * 256) * 3;
        float x = p[0], y = p[1], z = p[2];
        qq[k] = fmaf(x, x, fmaf(y, y, z * z));
        ax[k] = -2.f * x; ay[k] = -2.f * y; az[k] = -2.f * z;
        bst[k] = 3.4e38f;
      }
      __syncthreads();
#pragma unroll 2
      for (int j = 0; j < 512; ++j) {
        float4 c = sc[j];
#pragma unroll
        for (int k = 0; k < 8; ++k) {
          float t = fmaf(c.x, ax[k], c.w);
          t = fmaf(c.y, ay[k], t);
          t = fmaf(c.z, az[k], t);
          bst[k] = fminf(bst[k], t);
        }
      }
      int gr = which * 32768 + b * NUU + chunk * 2048 + tid;
#pragma unroll
      for (int k = 0; k < 8; ++k)
        atomicMin(&rowmin[gr + k * 256], fkey32(bst[k] + qq[k]));
    } else {
      // ---- cham_col: 32768 query-slots (gt vs off, gt vs up) ----
      int blk2 = blk - 256;
      int qb = blk2 >> 4;    // [0,16)
      int seg = blk2 & 15;   // [0,16)
      int which = qb >> 3;
      int b = (qb >> 1) & 3;
      int chunk = qb & 1;
      // stage candidate seg from off/up (512 pts, stride-3 source)
      const float* src = which ? up : off;
      if (tid < 128) {
        const float* sb = src + (size_t)b * NUU * 3 + (size_t)seg * 512 * 3;
        int i0 = tid * 4;
        const float4* s4 = (const float4*)(sb + (size_t)i0 * 3);
        float4 u0 = s4[0], u1 = s4[1], u2 = s4[2];
        sc[i0] = make_float4(u0.x, u0.y, u0.z,
                             fmaf(u0.x, u0.x, fmaf(u0.y, u0.y, u0.z * u0.z)));
        sc[i0 + 1] = make_float4(u0.w, u1.x, u1.y,
                                 fmaf(u0.w, u0.w, fmaf(u1.x, u1.x, u1.y * u1.y)));
        sc[i0 + 2] = make_float4(u1.z, u1.w, u2.x,
                                 fmaf(u1.z, u1.z, fmaf(u1.w, u1.w, u2.x * u2.x)));
        sc[i0 + 3] = make_float4(u2.y, u2.z, u2.w,
                                 fmaf(u2.y, u2.y, fmaf(u2.z, u2.z, u2.w * u2.w)));
      }
      const float* gq = gt + (size_t)b * NGG * 6 + (size_t)(chunk * 2048) * 6;
#pragma unroll
      for (int k = 0; k < 8; ++k) {
        const float* p = gq + (size_t)(tid + k * 256) * 6;
        float x = p[0], y = p[1], z = p[2];
        qq[k] = fmaf(x, x, fmaf(y, y, z * z));
        ax[k] = -2.f * x; ay[k] = -2.f * y; az[k] = -2.f * z;
        bst[k] = 3.4e38f;
      }
      __syncthreads();
#pragma unroll 2
      for (int j = 0; j < 512; ++j) {
        float4 c = sc[j];
#pragma unroll
        for (int k = 0; k < 8; ++k) {
          float t = fmaf(c.x, ax[k], c.w);
          t = fmaf(c.y, ay[k], t);
          t = fmaf(c.z, az[k], t);
          bst[k] = fminf(bst[k], t);
        }
      }
      int gc = which * 16384 + b * NGG + chunk * 2048 + tid;
#pragma unroll
      for (int k = 0; k < 8; ++k)
        atomicMin(&colmin[gc + k * 256], fkey32(bst[k] + qq[k]));
    }
  } else {
    // ---- argmin: 16384 queries (pts), candidates = gt segs ----
    int blk3 = blk - 512;    // [0,64)
    int qb = blk3 >> 3;      // [0,8)
    int seg = blk3 & 7;      // [0,8)
    int b = qb >> 1;
    int chunk = qb & 1;
    const float* gtb = gt + (size_t)b * NGG * 6 + (size_t)seg * 512 * 6;
    int i0 = tid * 2;
    const float4* g4 = (const float4*)(gtb + (size_t)i0 * 6);
    float4 u0 = g4[0], u1 = g4[1], u2 = g4[2];
    sc[i0] = make_float4(u0.x, u0.y, u0.z,
                         fmaf(u0.x, u0.x, fmaf(u0.y, u0.y, u0.z * u0.z)));
    sc[i0 + 1] = make_float4(u1.z, u1.w, u2.x,
                             fmaf(u1.z, u1.z, fmaf(u1.w, u1.w, u2.x * u2.x)));
    int idx[8];
    const float* pq = pts + (size_t)(b * NN + chunk * 2048) * 3;
#pragma unroll
    for (int k = 0; k < 8; ++k) {
      const float* p = pq + (size_t)(tid + k * 256) * 3;
      float x = p[0], y = p[1], z = p[2];
      ax[k] = -2.f * x; ay[k] = -2.f * y; az[k] = -2.f * z;
      bst[k] = 3.4e38f; idx[k] = 0;
    }
    __syncthreads();
#pragma unroll 2
    for (int j = 0; j < 512; ++j) {
      float4 c = sc[j];
#pragma unroll
      for (int k = 0; k < 8; ++k) {
        float t = fmaf(c.x, ax[k], c.w);
        t = fmaf(c.y, ay[k], t);
        t = fmaf(c.z, az[k], t);
        bool cc = t < bst[k];
        bst[k] = cc ? t : bst[k];
        idx[k] = cc ? j : idx[k];
      }
    }
    int q0 = b * NN + chunk * 2048 + tid;
    int base = seg * 512;
#pragma unroll
    for (int k = 0; k < 8; ++k)
      atomicMin(&keys[q0 + k * 256],
                ((unsigned long long)fkey32(bst[k]) << 32) | (unsigned)(base + idx[k]));
  }
}

// ------------- fused: postgather (blocks 0..63) + reduce mins (64..447) -
__global__ __launch_bounds__(256) void k_post(
    const float* __restrict__ ori_pre, const float* __restrict__ nor_pre,
    const float* __restrict__ gt, const unsigned long long* __restrict__ keys,
    const unsigned* __restrict__ rowmin, const unsigned* __restrict__ colmin,
    float* __restrict__ nor_gt, float* __restrict__ ori_pro, float* __restrict__ acc) {
  __shared__ float sb1[4], sb2[4];
  int blk = blockIdx.x;
  if (blk < 64) {
    int q = blk * 256 + threadIdx.x;
    int b = q >> 12;
    float ox = ori_pre[q * 3 + 0], oy = ori_pre[q * 3 + 1], oz = ori_pre[q * 3 + 2];
    float n1 = sqrtf(fmaf(ox, ox, fmaf(oy, oy, oz * oz)) + 1e-8f) + 1e-10f;
    ox /= n1; oy /= n1; oz /= n1;
    float px = nor_pre[q * 3 + 0], py = nor_pre[q * 3 + 1], pz = nor_pre[q * 3 + 2];
    float n2 = sqrtf(fmaf(px, px, fmaf(py, py, pz * pz)) + 1e-8f) + 1e-10f;
    px /= n2; py /= n2; pz /= n2;
    unsigned idx = (unsigned)(keys[q] & 0xffffffffULL);
    const float* g = gt + (size_t)b * NGG * 6 + (size_t)idx * 6 + 3;
    float gx = g[0], gy = g[1], gz = g[2];
    float dn = fmaf(gx, ox, fmaf(gy, oy, gz * oz));
    float vx = ox - gx * dn, vy = oy - gy * dn, vz = oz - gz * dn;
    float n3 = sqrtf(fmaf(vx, vx, fmaf(vy, vy, vz * vz)) + 1e-8f) + 1e-10f;
    vx /= n3; vy /= n3; vz /= n3;
    nor_gt[q * 3 + 0] = gx; nor_gt[q * 3 + 1] = gy; nor_gt[q * 3 + 2] = gz;
    ori_pro[q * 3 + 0] = vx; ori_pro[q * 3 + 1] = vy; ori_pro[q * 3 + 2] = vz;
    float na = fmaxf(sqrtf(fmaf(gx, gx, fmaf(gy, gy, gz * gz))), 1e-8f);
    float nb = fmaxf(sqrtf(fmaf(px, px, fmaf(py, py, pz * pz))), 1e-8f);
    float cs = fmaf(gx, px, fmaf(gy, py, gz * pz)) / (na * nb);
    float t_nor = 1.f - fabsf(cs);
    float t_ori = fabsf(dn);
    float s1 = block_sum_256(t_nor, sb1);
    float s2 = block_sum_256(t_ori, sb2);
    if (threadIdx.x == 0) {
      atomicAdd(&acc[1], s1);
      atomicAdd(&acc[2], s2);
    }
  } else {
    int rblk = blk - 64;   // [0,384)
    float v;
    int slot;
    if (rblk < 256) {
      int i = rblk * 256 + threadIdx.x;
      v = unfkey32(rowmin[i]);
      slot = (i >> 15) ? 5 : 3;   // 0=offset rows -> acc3, 1=up rows -> acc5
    } else {
      int i = (rblk - 256) * 256 + threadIdx.x;
      v = unfkey32(colmin[i]);
      slot = (i >> 14) ? 6 : 4;   // 0=offset cols -> acc4, 1=up cols -> acc6
    }
    float s = block_sum_256(v, sb1);
    if (threadIdx.x == 0) atomicAdd(&acc[slot], s);
  }
}

// ------------- KNN (K=6) among pts + fused loss_smooth -----------------
// 512 threads: 64 queries/block, 8 threads/query, interleaved candidates.
// Two-phase: A) exact top-6 of first 128 cands/thread -> threshold t6 (min
// over the query's 8 threads of their 6th-best: rigorous upper bound on the
// global 6th-NN distance); B) filter d<=t6, append to per-thread LDS list
// (cap 16, exact rescan fallback on overflow); drain; 8-way sorted merge.
__global__ __launch_bounds__(512) void k_knn_smooth(const float* __restrict__ pts,
                                                    const float* __restrict__ nor_gt,
                                                    const float* __restrict__ ori_pro,
                                                    float* __restrict__ acc) {
  __shared__ float4 sp[4096];                    // 64 KB
  __shared__ unsigned long long apbuf[512 * 16]; // 64 KB; reused as marr
  __shared__ float sbuf[8];
  int q_local = threadIdx.x >> 3;
  int t = threadIdx.x & 7;
  int q = blockIdx.x * 64 + q_local;
  int b = q >> 12;
  int n = q & 4095;
  const float* pb = pts + (size_t)b * NN * 3;
  for (int p = threadIdx.x; p < 4096; p += 512) {
    float x = pb[p * 3 + 0], y = pb[p * 3 + 1], z = pb[p * 3 + 2];
    sp[p] = make_float4(x, y, z, fmaf(x, x, fmaf(y, y, z * z)));
  }
  __syncthreads();
  float4 qp = sp[n];
  float qx2 = -2.f * qp.x, qy2 = -2.f * qp.y, qz2 = -2.f * qp.z;
  float d0 = 3.4e38f, d1 = 3.4e38f, d2 = 3.4e38f,
        d3 = 3.4e38f, d4 = 3.4e38f, d5 = 3.4e38f;
  int i0 = 0, i1 = 0, i2 = 0, i3 = 0, i4 = 0, i5 = 0;
  // ---- phase A: first 128 candidates per thread (global c = 0..1023) ----
  for (int j = 0; j < 128; ++j) {
    int c = (j << 3) | t;
    float4 p = sp[c];
    float d = fmaf(p.x, qx2, p.w);
    d = fmaf(p.y, qy2, d);
    d = fmaf(p.z, qz2, d);
    if (d < d5) ins6(d, c, d0, d1, d2, d3, d4, d5, i0, i1, i2, i3, i4, i5);
  }
  float t6 = d5;
  t6 = fminf(t6, __shfl_xor(t6, 1, 64));
  t6 = fminf(t6, __shfl_xor(t6, 2, 64));
  t6 = fminf(t6, __shfl_xor(t6, 4, 64));
  // ---- phase B: remaining 384 candidates, filtered append ----
  unsigned long long* ap = &apbuf[(size_t)threadIdx.x * 16];
  int cnt = 0;
#pragma unroll 4
  for (int j = 128; j < 512; ++j) {
    int c = (j << 3) | t;
    float4 p = sp[c];
    float d = fmaf(p.x, qx2, p.w);
    d = fmaf(p.y, qy2, d);
    d = fmaf(p.z, qz2, d);
    if (d <= t6) {
      if (cnt < 16)
        ap[cnt] = ((unsigned long long)__float_as_uint(d) << 32) | (unsigned)c;
      cnt++;
    }
  }
  if (cnt > 16) {
    // overflow (rare): exact rescan of phase B
    for (int j = 128; j < 512; ++j) {
      int c = (j << 3) | t;
      float4 p = sp[c];
      float d = fmaf(p.x, qx2, p.w);
      d = fmaf(p.y, qy2, d);
      d = fmaf(p.z, qz2, d);
      if (d < d5) ins6(d, c, d0, d1, d2, d3, d4, d5, i0, i1, i2, i3, i4, i5);
    }
  } else {
    for (int e = 0; e < cnt; ++e) {
      unsigned long long key = ap[e];
      float d = __uint_as_float((unsigned)(key >> 32));
      int c = (int)(key & 0xffffffffULL);
      if (d < d5) ins6(d, c, d0, d1, d2, d3, d4, d5, i0, i1, i2, i3, i4, i5);
    }
  }
  __syncthreads();   // appends consumed; reuse apbuf as marr
  unsigned long long* marr = apbuf;   // 64 queries x 48 keys
  unsigned long long* mq = &marr[(size_t)q_local * 48 + t * 6];
  // fkey32 REQUIRED: d' can be negative; raw float bits mis-order in u64.
  mq[0] = ((unsigned long long)fkey32(d0) << 32) | (unsigned)i0;
  mq[1] = ((unsigned long long)fkey32(d1) << 32) | (unsigned)i1;
  mq[2] = ((unsigned long long)fkey32(d2) << 32) | (unsigned)i2;
  mq[3] = ((unsigned long long)fkey32(d3) << 32) | (unsigned)i3;
  mq[4] = ((unsigned long long)fkey32(d4) << 32) | (unsigned)i4;
  mq[5] = ((unsigned long long)fkey32(d5) << 32) | (unsigned)i5;
  __syncthreads();
  float sum = 0.f;
  if (t == 0) {
    float ngx = nor_gt[q * 3 + 0], ngy = nor_gt[q * 3 + 1], ngz = nor_gt[q * 3 + 2];
    float box = ori_pro[q * 3 + 0], boy = ori_pro[q * 3 + 1], boz = ori_pro[q * 3 + 2];
    float rx = boy * ngz - boz * ngy;
    float ry = boz * ngx - box * ngz;
    float rz = box * ngy - boy * ngx;
    float nbo = fmaxf(sqrtf(fmaf(box, box, fmaf(boy, boy, boz * boz))), 1e-8f);
    float nrot = fmaxf(sqrtf(fmaf(rx, rx, fmaf(ry, ry, rz * rz))), 1e-8f);
    const unsigned long long* mrow = &marr[(size_t)q_local * 48];
    int head[8] = {0, 0, 0, 0, 0, 0, 0, 0};
    for (int k = 0; k < 6; ++k) {
      unsigned long long best = ~0ULL;
      int bl = 0;
#pragma unroll
      for (int l = 0; l < 8; ++l) {
        unsigned long long v = mrow[l * 6 + head[l]];
        if (v < best) { best = v; bl = l; }
      }
#pragma unroll
      for (int l = 0; l < 8; ++l) head[l] += (l == bl) ? 1 : 0;
      int id = (int)(best & 0xffffffffULL);
      const float* gn = &nor_gt[(size_t)(b * 4096 + id) * 3];
      const float* go = &ori_pro[(size_t)(b * 4096 + id) * 3];
      float gnx = gn[0], gny = gn[1], gnz = gn[2];
      float gox = go[0], goy = go[1], goz = go[2];
      float nd = fmaf(gnx, ngx, fmaf(gny, ngy, gnz * ngz));
      float wv = (expf(-nd / 0.3f) * 10.f + 1.f) < 4.f ? 1.f : 5.f;
      float ngo = fmaxf(sqrtf(fmaf(gox, gox, fmaf(goy, goy, goz * goz))), 1e-8f);
      float c0 = fmaf(gox, box, fmaf(goy, boy, goz * boz)) / (ngo * nbo);
      float c1 = fmaf(gox, rx, fmaf(goy, ry, goz * rz)) / (ngo * nrot);
      float cosv = fminf(1.f - fabsf(c0), 1.f - fabsf(c1));
      sum += wv * cosv;
    }
  }
  float s = block_sum_512(sum, sbuf);
  if (threadIdx.x == 0) atomicAdd(&acc[0], s);
}

// ------------- combine to the 7 outputs --------------------------------
__global__ void k_finalize(const float* __restrict__ acc, float* __restrict__ out) {
  if (threadIdx.x == 0 && blockIdx.x == 0) {
    float loss_smooth = acc[0] / 98304.f;            // B*N*K
    float loss_nor = acc[1] / 16384.f;               // B*N
    float loss_nor_ori = acc[2] / 16384.f;
    float lco = acc[3] / 32768.f + acc[4] / 16384.f; // B*NU rows + B*NG cols
    float lc = acc[5] / 32768.f + acc[6] / 16384.f;
    float loss_cd = lc + 0.4f * lco;
    float loss = loss_smooth + loss_nor + 0.1f * loss_nor_ori + 200.f * loss_cd;
    out[0] = loss;
    out[1] = loss_smooth;
    out[2] = loss_nor;
    out[3] = lco;
    out[4] = loss_nor_ori;
    out[5] = lc;
    out[6] = lc;
  }
}

extern "C" void kernel_launch(void* const* d_in, const int* in_sizes, int n_in,
                              void* d_out, int out_size, void* d_ws, size_t ws_size,
                              hipStream_t stream) {
  (void)in_sizes; (void)n_in; (void)out_size; (void)ws_size;
  const float* ori_pre = (const float*)d_in[0];
  const float* nor_pre = (const float*)d_in[1];
  const float* xyz_up = (const float*)d_in[2];
  const float* xyz_off = (const float*)d_in[3];
  const float* pts = (const float*)d_in[4];
  const float* gt = (const float*)d_in[5];
  float* out = (float*)d_out;
  char* ws = (char*)d_ws;

  float* acc = (float*)(ws + 0);                                   // 16 floats
  unsigned long long* keys = (unsigned long long*)(ws + 512);      // 16384 u64 = 128 KB
  unsigned* rowmin = (unsigned*)(ws + 512 + 131072);               // 65536 u32 = 256 KB
  unsigned* colmin = (unsigned*)(ws + 512 + 131072 + 262144);      // 32768 u32 = 128 KB
  float* nor_gt = (float*)(ws + 512 + 131072 + 262144 + 131072);   // 49152 f32 = 192 KB
  float* ori_pro = (float*)(ws + 512 + 131072 + 262144 + 131072 + 196608);

  hipMemsetAsync(acc, 0, 64, stream);
  hipMemsetAsync(ws + 512, 0xFF, 131072 + 262144 + 131072, stream);

  k_scan<<<576, 256, 0, stream>>>(pts, gt, xyz_up, xyz_off, keys, rowmin, colmin);
  k_post<<<448, 256, 0, stream>>>(ori_pre, nor_pre, gt, keys, rowmin, colmin,
                                  nor_gt, ori_pro, acc);
  k_knn_smooth<<<256, 512, 0, stream>>>(pts, nor_gt, ori_pro, acc);
  k_finalize<<<1, 64, 0, stream>>>(acc, out);
}

// Round 7
// 264.574 us; speedup vs baseline: 2.1490x; 1.0627x over previous
//
#include <hip/hip_runtime.h>
#include <stdint.h>

#define NN 4096
#define NGG 4096
#define NUU 8192

// monotone float->uint mapping (order-preserving incl. negatives)
__device__ __forceinline__ unsigned fkey32(float f) {
  unsigned u = __float_as_uint(f);
  return u ^ (((int)u >> 31) | 0x80000000u);
}
__device__ __forceinline__ float unfkey32(unsigned k) {
  unsigned m = (k & 0x80000000u) ? 0x80000000u : 0xFFFFFFFFu;
  return __uint_as_float(k ^ m);
}

// ---------------- block-wide sum (blockDim.x == 256) -------------------
__device__ __forceinline__ float block_sum_256(float v, float* sbuf) {
#pragma unroll
  for (int o = 32; o > 0; o >>= 1) v += __shfl_down(v, o, 64);
  int lane = threadIdx.x & 63;
  int w = threadIdx.x >> 6;
  if (lane == 0) sbuf[w] = v;
  __syncthreads();
  float r = 0.f;
  if (threadIdx.x == 0) r = sbuf[0] + sbuf[1] + sbuf[2] + sbuf[3];
  __syncthreads();
  return r;
}

// sorted 6-element insert of (d, ci), ascending by d
__device__ __forceinline__ void ins6(float d, int ci,
                                     float& d0, float& d1, float& d2,
                                     float& d3, float& d4, float& d5,
                                     int& i0, int& i1, int& i2,
                                     int& i3, int& i4, int& i5) {
  bool cc; float nd; int ni;
  cc = d < d0; nd = cc ? d : d0; d = cc ? d0 : d; ni = cc ? ci : i0; ci = cc ? i0 : ci; d0 = nd; i0 = ni;
  cc = d < d1; nd = cc ? d : d1; d = cc ? d1 : d; ni = cc ? ci : i1; ci = cc ? i1 : ci; d1 = nd; i1 = ni;
  cc = d < d2; nd = cc ? d : d2; d = cc ? d2 : d; ni = cc ? ci : i2; ci = cc ? i2 : ci; d2 = nd; i2 = ni;
  cc = d < d3; nd = cc ? d : d3; d = cc ? d3 : d; ni = cc ? ci : i3; ci = cc ? i3 : ci; d3 = nd; i3 = ni;
  cc = d < d4; nd = cc ? d : d4; d = cc ? d4 : d; ni = cc ? ci : i4; ci = cc ? i4 : ci; d4 = nd; i4 = ni;
  cc = d < d5; nd = cc ? d : d5;                  ni = cc ? ci : i5;                    d5 = nd; i5 = ni;
}

// ---------------- fused scan (R3-proven Q=4 version) -------------------
// blocks [0,512): cham_row  (65536 queries, gt candidates, 8 segs x 512)
// blocks [512,1024): cham_col (32768 queries, up/off candidates, 16 segs x 512)
// blocks [1024,1280): argmin (16384 queries, gt candidates, 16 segs x 256)
__global__ __launch_bounds__(256) void k_scan(const float* __restrict__ pts,
                                              const float* __restrict__ gt,
                                              const float* __restrict__ up,
                                              const float* __restrict__ off,
                                              unsigned long long* __restrict__ keys,
                                              unsigned* __restrict__ rowmin,
                                              unsigned* __restrict__ colmin) {
  __shared__ float4 sc[512];   // 8 KB
  int blk = blockIdx.x;
  int tid = threadIdx.x;

  if (blk < 512) {
    int qb = blk >> 3;           // [0,64)
    int seg = blk & 7;           // [0,8)
    int wb = qb >> 3;            // [0,8)
    int which = wb >> 2;         // 0=off, 1=up
    int b = wb & 3;
    int r0 = (qb & 7) * 1024 + tid * 4;   // [0,8192)
    {
      const float* gtb = gt + (size_t)b * NGG * 6 + (size_t)seg * 512 * 6;
      int i0 = tid * 2;
      const float4* g4 = (const float4*)(gtb + (size_t)i0 * 6);
      float4 u0 = g4[0], u1 = g4[1], u2 = g4[2];
      sc[i0] = make_float4(u0.x, u0.y, u0.z,
                           fmaf(u0.x, u0.x, fmaf(u0.y, u0.y, u0.z * u0.z)));
      sc[i0 + 1] = make_float4(u1.z, u1.w, u2.x,
                               fmaf(u1.z, u1.z, fmaf(u1.w, u1.w, u2.x * u2.x)));
    }
    const float* src = which ? up : off;
    const float4* s4 = (const float4*)src;
    size_t fb = ((size_t)(b * NUU + r0) * 3) >> 2;
    float4 A = s4[fb], B = s4[fb + 1], C = s4[fb + 2];
    float q0x = A.x, q0y = A.y, q0z = A.z;
    float q1x = A.w, q1y = B.x, q1z = B.y;
    float q2x = B.z, q2y = B.w, q2z = C.x;
    float q3x = C.y, q3y = C.z, q3z = C.w;
    float qq0 = fmaf(q0x, q0x, fmaf(q0y, q0y, q0z * q0z));
    float qq1 = fmaf(q1x, q1x, fmaf(q1y, q1y, q1z * q1z));
    float qq2 = fmaf(q2x, q2x, fmaf(q2y, q2y, q2z * q2z));
    float qq3 = fmaf(q3x, q3x, fmaf(q3y, q3y, q3z * q3z));
    float a0x = -2.f * q0x, a0y = -2.f * q0y, a0z = -2.f * q0z;
    float a1x = -2.f * q1x, a1y = -2.f * q1y, a1z = -2.f * q1z;
    float a2x = -2.f * q2x, a2y = -2.f * q2y, a2z = -2.f * q2z;
    float a3x = -2.f * q3x, a3y = -2.f * q3y, a3z = -2.f * q3z;
    __syncthreads();
    float b0 = 3.4e38f, b1 = 3.4e38f, b2 = 3.4e38f, b3 = 3.4e38f;
#pragma unroll 4
    for (int j = 0; j < 512; ++j) {
      float4 c = sc[j];
      float t;
      t = fmaf(c.x, a0x, c.w); t = fmaf(c.y, a0y, t); t = fmaf(c.z, a0z, t); b0 = fminf(b0, t);
      t = fmaf(c.x, a1x, c.w); t = fmaf(c.y, a1y, t); t = fmaf(c.z, a1z, t); b1 = fminf(b1, t);
      t = fmaf(c.x, a2x, c.w); t = fmaf(c.y, a2y, t); t = fmaf(c.z, a2z, t); b2 = fminf(b2, t);
      t = fmaf(c.x, a3x, c.w); t = fmaf(c.y, a3y, t); t = fmaf(c.z, a3z, t); b3 = fminf(b3, t);
    }
    int gr = which * 32768 + b * NUU + r0;
    atomicMin(&rowmin[gr + 0], fkey32(b0 + qq0));
    atomicMin(&rowmin[gr + 1], fkey32(b1 + qq1));
    atomicMin(&rowmin[gr + 2], fkey32(b2 + qq2));
    atomicMin(&rowmin[gr + 3], fkey32(b3 + qq3));

  } else if (blk < 1024) {
    int blk2 = blk - 512;
    int qb = blk2 >> 4;          // [0,32)
    int seg = blk2 & 15;         // [0,16)
    int which = qb >> 4;         // 0=off, 1=up
    int b = (qb >> 2) & 3;
    int m0 = (qb & 3) * 1024 + tid * 4;   // [0,4096)
    const float* src = which ? up : off;
    if (tid < 128) {
      const float* sb = src + (size_t)b * NUU * 3 + (size_t)seg * 512 * 3;
      int i0 = tid * 4;
      const float4* s4 = (const float4*)(sb + (size_t)i0 * 3);
      float4 u0 = s4[0], u1 = s4[1], u2 = s4[2];
      sc[i0] = make_float4(u0.x, u0.y, u0.z,
                           fmaf(u0.x, u0.x, fmaf(u0.y, u0.y, u0.z * u0.z)));
      sc[i0 + 1] = make_float4(u0.w, u1.x, u1.y,
                               fmaf(u0.w, u0.w, fmaf(u1.x, u1.x, u1.y * u1.y)));
      sc[i0 + 2] = make_float4(u1.z, u1.w, u2.x,
                               fmaf(u1.z, u1.z, fmaf(u1.w, u1.w, u2.x * u2.x)));
      sc[i0 + 3] = make_float4(u2.y, u2.z, u2.w,
                               fmaf(u2.y, u2.y, fmaf(u2.z, u2.z, u2.w * u2.w)));
    }
    const float* g = gt + (size_t)b * NGG * 6 + (size_t)m0 * 6;
    float q0x = g[0],  q0y = g[1],  q0z = g[2];
    float q1x = g[6],  q1y = g[7],  q1z = g[8];
    float q2x = g[12], q2y = g[13], q2z = g[14];
    float q3x = g[18], q3y = g[19], q3z = g[20];
    float qq0 = fmaf(q0x, q0x, fmaf(q0y, q0y, q0z * q0z));
    float qq1 = fmaf(q1x, q1x, fmaf(q1y, q1y, q1z * q1z));
    float qq2 = fmaf(q2x, q2x, fmaf(q2y, q2y, q2z * q2z));
    float qq3 = fmaf(q3x, q3x, fmaf(q3y, q3y, q3z * q3z));
    float a0x = -2.f * q0x, a0y = -2.f * q0y, a0z = -2.f * q0z;
    float a1x = -2.f * q1x, a1y = -2.f * q1y, a1z = -2.f * q1z;
    float a2x = -2.f * q2x, a2y = -2.f * q2y, a2z = -2.f * q2z;
    float a3x = -2.f * q3x, a3y = -2.f * q3y, a3z = -2.f * q3z;
    __syncthreads();
    float b0 = 3.4e38f, b1 = 3.4e38f, b2 = 3.4e38f, b3 = 3.4e38f;
#pragma unroll 4
    for (int j = 0; j < 512; ++j) {
      float4 c = sc[j];
      float t;
      t = fmaf(c.x, a0x, c.w); t = fmaf(c.y, a0y, t); t = fmaf(c.z, a0z, t); b0 = fminf(b0, t);
      t = fmaf(c.x, a1x, c.w); t = fmaf(c.y, a1y, t); t = fmaf(c.z, a1z, t); b1 = fminf(b1, t);
      t = fmaf(c.x, a2x, c.w); t = fmaf(c.y, a2y, t); t = fmaf(c.z, a2z, t); b2 = fminf(b2, t);
      t = fmaf(c.x, a3x, c.w); t = fmaf(c.y, a3y, t); t = fmaf(c.z, a3z, t); b3 = fminf(b3, t);
    }
    int gc = which * 16384 + b * NGG + m0;
    atomicMin(&colmin[gc + 0], fkey32(b0 + qq0));
    atomicMin(&colmin[gc + 1], fkey32(b1 + qq1));
    atomicMin(&colmin[gc + 2], fkey32(b2 + qq2));
    atomicMin(&colmin[gc + 3], fkey32(b3 + qq3));

  } else {
    int blk3 = blk - 1024;
    int qb = blk3 >> 4;          // [0,16)
    int seg = blk3 & 15;         // [0,16), 256 candidates each
    int b = qb >> 2;
    int m0 = (qb & 3) * 1024 + tid * 4;   // [0,4096)
    if (tid < 128) {
      const float* gtb = gt + (size_t)b * NGG * 6 + (size_t)seg * 256 * 6;
      int i0 = tid * 2;
      const float4* g4 = (const float4*)(gtb + (size_t)i0 * 6);
      float4 u0 = g4[0], u1 = g4[1], u2 = g4[2];
      sc[i0] = make_float4(u0.x, u0.y, u0.z,
                           fmaf(u0.x, u0.x, fmaf(u0.y, u0.y, u0.z * u0.z)));
      sc[i0 + 1] = make_float4(u1.z, u1.w, u2.x,
                               fmaf(u1.z, u1.z, fmaf(u1.w, u1.w, u2.x * u2.x)));
    }
    size_t fb = ((size_t)(b * NN + m0) * 3) >> 2;
    const float4* p4 = (const float4*)pts;
    float4 A = p4[fb], B = p4[fb + 1], C = p4[fb + 2];
    float q0x = A.x, q0y = A.y, q0z = A.z;
    float q1x = A.w, q1y = B.x, q1z = B.y;
    float q2x = B.z, q2y = B.w, q2z = C.x;
    float q3x = C.y, q3y = C.z, q3z = C.w;
    float a0x = -2.f * q0x, a0y = -2.f * q0y, a0z = -2.f * q0z;
    float a1x = -2.f * q1x, a1y = -2.f * q1y, a1z = -2.f * q1z;
    float a2x = -2.f * q2x, a2y = -2.f * q2y, a2z = -2.f * q2z;
    float a3x = -2.f * q3x, a3y = -2.f * q3y, a3z = -2.f * q3z;
    __syncthreads();
    float b0 = 3.4e38f, b1 = 3.4e38f, b2 = 3.4e38f, b3 = 3.4e38f;
    int i0 = 0, i1 = 0, i2 = 0, i3 = 0;
#pragma unroll 4
    for (int j = 0; j < 256; ++j) {
      float4 c = sc[j];
      float t; bool cc;
      t = fmaf(c.x, a0x, c.w); t = fmaf(c.y, a0y, t); t = fmaf(c.z, a0z, t);
      cc = t < b0; b0 = cc ? t : b0; i0 = cc ? j : i0;
      t = fmaf(c.x, a1x, c.w); t = fmaf(c.y, a1y, t); t = fmaf(c.z, a1z, t);
      cc = t < b1; b1 = cc ? t : b1; i1 = cc ? j : i1;
      t = fmaf(c.x, a2x, c.w); t = fmaf(c.y, a2y, t); t = fmaf(c.z, a2z, t);
      cc = t < b2; b2 = cc ? t : b2; i2 = cc ? j : i2;
      t = fmaf(c.x, a3x, c.w); t = fmaf(c.y, a3y, t); t = fmaf(c.z, a3z, t);
      cc = t < b3; b3 = cc ? t : b3; i3 = cc ? j : i3;
    }
    int q = b * NN + m0;
    int base = seg * 256;
    atomicMin(&keys[q + 0], ((unsigned long long)fkey32(b0) << 32) | (unsigned)(base + i0));
    atomicMin(&keys[q + 1], ((unsigned long long)fkey32(b1) << 32) | (unsigned)(base + i1));
    atomicMin(&keys[q + 2], ((unsigned long long)fkey32(b2) << 32) | (unsigned)(base + i2));
    atomicMin(&keys[q + 3], ((unsigned long long)fkey32(b3) << 32) | (unsigned)(base + i3));
  }
}

// ------------- fused: postgather (blocks 0..63) + reduce mins (64..447) -
__global__ __launch_bounds__(256) void k_post(
    const float* __restrict__ ori_pre, const float* __restrict__ nor_pre,
    const float* __restrict__ gt, const unsigned long long* __restrict__ keys,
    const unsigned* __restrict__ rowmin, const unsigned* __restrict__ colmin,
    float* __restrict__ nor_gt, float* __restrict__ ori_pro, float* __restrict__ acc) {
  __shared__ float sb1[4], sb2[4];
  int blk = blockIdx.x;
  if (blk < 64) {
    int q = blk * 256 + threadIdx.x;
    int b = q >> 12;
    float ox = ori_pre[q * 3 + 0], oy = ori_pre[q * 3 + 1], oz = ori_pre[q * 3 + 2];
    float n1 = sqrtf(fmaf(ox, ox, fmaf(oy, oy, oz * oz)) + 1e-8f) + 1e-10f;
    ox /= n1; oy /= n1; oz /= n1;
    float px = nor_pre[q * 3 + 0], py = nor_pre[q * 3 + 1], pz = nor_pre[q * 3 + 2];
    float n2 = sqrtf(fmaf(px, px, fmaf(py, py, pz * pz)) + 1e-8f) + 1e-10f;
    px /= n2; py /= n2; pz /= n2;
    unsigned idx = (unsigned)(keys[q] & 0xffffffffULL);
    const float* g = gt + (size_t)b * NGG * 6 + (size_t)idx * 6 + 3;
    float gx = g[0], gy = g[1], gz = g[2];
    float dn = fmaf(gx, ox, fmaf(gy, oy, gz * oz));
    float vx = ox - gx * dn, vy = oy - gy * dn, vz = oz - gz * dn;
    float n3 = sqrtf(fmaf(vx, vx, fmaf(vy, vy, vz * vz)) + 1e-8f) + 1e-10f;
    vx /= n3; vy /= n3; vz /= n3;
    nor_gt[q * 3 + 0] = gx; nor_gt[q * 3 + 1] = gy; nor_gt[q * 3 + 2] = gz;
    ori_pro[q * 3 + 0] = vx; ori_pro[q * 3 + 1] = vy; ori_pro[q * 3 + 2] = vz;
    float na = fmaxf(sqrtf(fmaf(gx, gx, fmaf(gy, gy, gz * gz))), 1e-8f);
    float nb = fmaxf(sqrtf(fmaf(px, px, fmaf(py, py, pz * pz))), 1e-8f);
    float cs = fmaf(gx, px, fmaf(gy, py, gz * pz)) / (na * nb);
    float t_nor = 1.f - fabsf(cs);
    float t_ori = fabsf(dn);
    float s1 = block_sum_256(t_nor, sb1);
    float s2 = block_sum_256(t_ori, sb2);
    if (threadIdx.x == 0) {
      atomicAdd(&acc[1], s1);
      atomicAdd(&acc[2], s2);
    }
  } else {
    int rblk = blk - 64;   // [0,384)
    float v;
    int slot;
    if (rblk < 256) {
      int i = rblk * 256 + threadIdx.x;
      v = unfkey32(rowmin[i]);
      slot = (i >> 15) ? 5 : 3;
    } else {
      int i = (rblk - 256) * 256 + threadIdx.x;
      v = unfkey32(colmin[i]);
      slot = (i >> 14) ? 6 : 4;
    }
    float s = block_sum_256(v, sb1);
    if (threadIdx.x == 0) atomicAdd(&acc[slot], s);
  }
}

// ------------- KNN (K=6) among pts + fused loss_smooth -----------------
// 256 threads: 32 queries/block, 8 threads/query. Phase A: branchless
// distance-only top-6 of first 128 cands/thread -> t6 (shfl-min over the
// query's 8 lanes; rigorous >= global 6th-NN). Phase B: full 512-cand pass,
// filter d<=t6, append INDEX to stride-15 u32 LDS list (cap 15; exact
// rescan fallback on overflow). Drain+recompute, ins6, 8-way merge.
__global__ __launch_bounds__(256) void k_knn_smooth(const float* __restrict__ pts,
                                                    const float* __restrict__ nor_gt,
                                                    const float* __restrict__ ori_pro,
                                                    float* __restrict__ acc) {
  __shared__ float4 sp[4096];               // 64 KB
  __shared__ unsigned long long mbuf[1920]; // 15.36 KB: ap (u32 view) then marr
  __shared__ float sbuf[4];
  unsigned* apbuf = (unsigned*)mbuf;
  int q_local = threadIdx.x >> 3;   // [0,32)
  int t = threadIdx.x & 7;
  int q = blockIdx.x * 32 + q_local;
  int b = q >> 12;
  int n = q & 4095;
  const float* pb = pts + (size_t)b * NN * 3;
  for (int p = threadIdx.x; p < 4096; p += 256) {
    float x = pb[p * 3 + 0], y = pb[p * 3 + 1], z = pb[p * 3 + 2];
    sp[p] = make_float4(x, y, z, fmaf(x, x, fmaf(y, y, z * z)));
  }
  __syncthreads();
  float4 qp = sp[n];
  float qx2 = -2.f * qp.x, qy2 = -2.f * qp.y, qz2 = -2.f * qp.z;
  // ---- phase A: branchless sorted top-6 DISTANCES of first 128 ----
  float d0 = 3.4e38f, d1 = 3.4e38f, d2 = 3.4e38f,
        d3 = 3.4e38f, d4 = 3.4e38f, d5 = 3.4e38f;
#pragma unroll 4
  for (int j = 0; j < 128; ++j) {
    int c = (j << 3) | t;
    float4 p = sp[c];
    float d = fmaf(p.x, qx2, p.w);
    d = fmaf(p.y, qy2, d);
    d = fmaf(p.z, qz2, d);
    float v = d, hi;
    hi = fmaxf(v, d0); d0 = fminf(v, d0); v = hi;
    hi = fmaxf(v, d1); d1 = fminf(v, d1); v = hi;
    hi = fmaxf(v, d2); d2 = fminf(v, d2); v = hi;
    hi = fmaxf(v, d3); d3 = fminf(v, d3); v = hi;
    hi = fmaxf(v, d4); d4 = fminf(v, d4); v = hi;
    d5 = fminf(v, d5);
  }
  float t6 = d5;
  t6 = fminf(t6, __shfl_xor(t6, 1, 64));
  t6 = fminf(t6, __shfl_xor(t6, 2, 64));
  t6 = fminf(t6, __shfl_xor(t6, 4, 64));
  // ---- phase B: full pass, filtered index-append ----
  unsigned* ap = &apbuf[(size_t)threadIdx.x * 15];
  int cnt = 0;
#pragma unroll 4
  for (int j = 0; j < 512; ++j) {
    int c = (j << 3) | t;
    float4 p = sp[c];
    float d = fmaf(p.x, qx2, p.w);
    d = fmaf(p.y, qy2, d);
    d = fmaf(p.z, qz2, d);
    if (d <= t6) {
      if (cnt < 15) ap[cnt] = (unsigned)c;
      cnt++;
    }
  }
  // ---- build per-thread top-6 (with indices) ----
  int i0 = 0, i1 = 0, i2 = 0, i3 = 0, i4 = 0, i5 = 0;
  d0 = d1 = d2 = d3 = d4 = d5 = 3.4e38f;
  if (cnt > 15) {
    // overflow (rare): exact full rescan with sorted insert
    for (int j = 0; j < 512; ++j) {
      int c = (j << 3) | t;
      float4 p = sp[c];
      float d = fmaf(p.x, qx2, p.w);
      d = fmaf(p.y, qy2, d);
      d = fmaf(p.z, qz2, d);
      if (d < d5) ins6(d, c, d0, d1, d2, d3, d4, d5, i0, i1, i2, i3, i4, i5);
    }
  } else {
    for (int e = 0; e < cnt; ++e) {
      int c = (int)ap[e];
      float4 p = sp[c];
      float d = fmaf(p.x, qx2, p.w);
      d = fmaf(p.y, qy2, d);
      d = fmaf(p.z, qz2, d);
      if (d < d5) ins6(d, c, d0, d1, d2, d3, d4, d5, i0, i1, i2, i3, i4, i5);
    }
  }
  __syncthreads();   // ap consumed; reuse mbuf as marr
  unsigned long long* marr = mbuf;    // stride 50 u64 per query (32 x 50)
  unsigned long long* mq = &marr[(size_t)q_local * 50 + t * 6];
  // fkey32 REQUIRED: d' can be negative; raw float bits mis-order in u64.
  mq[0] = ((unsigned long long)fkey32(d0) << 32) | (unsigned)i0;
  mq[1] = ((unsigned long long)fkey32(d1) << 32) | (unsigned)i1;
  mq[2] = ((unsigned long long)fkey32(d2) << 32) | (unsigned)i2;
  mq[3] = ((unsigned long long)fkey32(d3) << 32) | (unsigned)i3;
  mq[4] = ((unsigned long long)fkey32(d4) << 32) | (unsigned)i4;
  mq[5] = ((unsigned long long)fkey32(d5) << 32) | (unsigned)i5;
  __syncthreads();
  float sum = 0.f;
  if (t == 0) {
    float ngx = nor_gt[q * 3 + 0], ngy = nor_gt[q * 3 + 1], ngz = nor_gt[q * 3 + 2];
    float box = ori_pro[q * 3 + 0], boy = ori_pro[q * 3 + 1], boz = ori_pro[q * 3 + 2];
    float rx = boy * ngz - boz * ngy;
    float ry = boz * ngx - box * ngz;
    float rz = box * ngy - boy * ngx;
    float nbo = fmaxf(sqrtf(fmaf(box, box, fmaf(boy, boy, boz * boz))), 1e-8f);
    float nrot = fmaxf(sqrtf(fmaf(rx, rx, fmaf(ry, ry, rz * rz))), 1e-8f);
    const unsigned long long* mrow = &marr[(size_t)q_local * 50];
    int head[8] = {0, 0, 0, 0, 0, 0, 0, 0};
    for (int k = 0; k < 6; ++k) {
      unsigned long long best = ~0ULL;
      int bl = 0;
#pragma unroll
      for (int l = 0; l < 8; ++l) {
        unsigned long long v = mrow[l * 6 + head[l]];
        if (v < best) { best = v; bl = l; }
      }
#pragma unroll
      for (int l = 0; l < 8; ++l) head[l] += (l == bl) ? 1 : 0;
      int id = (int)(best & 0xffffffffULL);
      const float* gn = &nor_gt[(size_t)(b * 4096 + id) * 3];
      const float* go = &ori_pro[(size_t)(b * 4096 + id) * 3];
      float gnx = gn[0], gny = gn[1], gnz = gn[2];
      float gox = go[0], goy = go[1], goz = go[2];
      float nd = fmaf(gnx, ngx, fmaf(gny, ngy, gnz * ngz));
      float wv = (expf(-nd / 0.3f) * 10.f + 1.f) < 4.f ? 1.f : 5.f;
      float ngo = fmaxf(sqrtf(fmaf(gox, gox, fmaf(goy, goy, goz * goz))), 1e-8f);
      float c0 = fmaf(gox, box, fmaf(goy, boy, goz * boz)) / (ngo * nbo);
      float c1 = fmaf(gox, rx, fmaf(goy, ry, goz * rz)) / (ngo * nrot);
      float cosv = fminf(1.f - fabsf(c0), 1.f - fabsf(c1));
      sum += wv * cosv;
    }
  }
  float s = block_sum_256(sum, sbuf);
  if (threadIdx.x == 0) atomicAdd(&acc[0], s);
}

// ------------- combine to the 7 outputs --------------------------------
__global__ void k_finalize(const float* __restrict__ acc, float* __restrict__ out) {
  if (threadIdx.x == 0 && blockIdx.x == 0) {
    float loss_smooth = acc[0] / 98304.f;            // B*N*K
    float loss_nor = acc[1] / 16384.f;               // B*N
    float loss_nor_ori = acc[2] / 16384.f;
    float lco = acc[3] / 32768.f + acc[4] / 16384.f; // B*NU rows + B*NG cols
    float lc = acc[5] / 32768.f + acc[6] / 16384.f;
    float loss_cd = lc + 0.4f * lco;
    float loss = loss_smooth + loss_nor + 0.1f * loss_nor_ori + 200.f * loss_cd;
    out[0] = loss;
    out[1] = loss_smooth;
    out[2] = loss_nor;
    out[3] = lco;
    out[4] = loss_nor_ori;
    out[5] = lc;
    out[6] = lc;
  }
}

extern "C" void kernel_launch(void* const* d_in, const int* in_sizes, int n_in,
                              void* d_out, int out_size, void* d_ws, size_t ws_size,
                              hipStream_t stream) {
  (void)in_sizes; (void)n_in; (void)out_size; (void)ws_size;
  const float* ori_pre = (const float*)d_in[0];
  const float* nor_pre = (const float*)d_in[1];
  const float* xyz_up = (const float*)d_in[2];
  const float* xyz_off = (const float*)d_in[3];
  const float* pts = (const float*)d_in[4];
  const float* gt = (const float*)d_in[5];
  float* out = (float*)d_out;
  char* ws = (char*)d_ws;

  float* acc = (float*)(ws + 0);                                   // 16 floats
  unsigned long long* keys = (unsigned long long*)(ws + 512);      // 16384 u64 = 128 KB
  unsigned* rowmin = (unsigned*)(ws + 512 + 131072);               // 65536 u32 = 256 KB
  unsigned* colmin = (unsigned*)(ws + 512 + 131072 + 262144);      // 32768 u32 = 128 KB
  float* nor_gt = (float*)(ws + 512 + 131072 + 262144 + 131072);   // 49152 f32 = 192 KB
  float* ori_pro = (float*)(ws + 512 + 131072 + 262144 + 131072 + 196608);

  hipMemsetAsync(acc, 0, 64, stream);
  hipMemsetAsync(ws + 512, 0xFF, 131072 + 262144 + 131072, stream);

  k_scan<<<1280, 256, 0, stream>>>(pts, gt, xyz_up, xyz_off, keys, rowmin, colmin);
  k_post<<<448, 256, 0, stream>>>(ori_pre, nor_pre, gt, keys, rowmin, colmin,
                                  nor_gt, ori_pro, acc);
  k_knn_smooth<<<512, 256, 0, stream>>>(pts, nor_gt, ori_pro, acc);
  k_finalize<<<1, 64, 0, stream>>>(acc, out);
}

// Round 8
// 228.473 us; speedup vs baseline: 2.4886x; 1.1580x over previous
//
#include <hip/hip_runtime.h>
#include <stdint.h>

#define NN 4096
#define NGG 4096
#define NUU 8192

// monotone float->uint mapping (order-preserving incl. negatives)
__device__ __forceinline__ unsigned fkey32(float f) {
  unsigned u = __float_as_uint(f);
  return u ^ (((int)u >> 31) | 0x80000000u);
}
__device__ __forceinline__ float unfkey32(unsigned k) {
  unsigned m = (k & 0x80000000u) ? 0x80000000u : 0xFFFFFFFFu;
  return __uint_as_float(k ^ m);
}

// ---------------- block-wide sum (blockDim.x == 256) -------------------
__device__ __forceinline__ float block_sum_256(float v, float* sbuf) {
#pragma unroll
  for (int o = 32; o > 0; o >>= 1) v += __shfl_down(v, o, 64);
  int lane = threadIdx.x & 63;
  int w = threadIdx.x >> 6;
  if (lane == 0) sbuf[w] = v;
  __syncthreads();
  float r = 0.f;
  if (threadIdx.x == 0) r = sbuf[0] + sbuf[1] + sbuf[2] + sbuf[3];
  __syncthreads();
  return r;
}

// ---------------- fused scan (R3-proven Q=4 version) -------------------
// blocks [0,512): cham_row  (65536 queries, gt candidates, 8 segs x 512)
// blocks [512,1024): cham_col (32768 queries, up/off candidates, 16 segs x 512)
// blocks [1024,1280): argmin (16384 queries, gt candidates, 16 segs x 256)
__global__ __launch_bounds__(256) void k_scan(const float* __restrict__ pts,
                                              const float* __restrict__ gt,
                                              const float* __restrict__ up,
                                              const float* __restrict__ off,
                                              unsigned long long* __restrict__ keys,
                                              unsigned* __restrict__ rowmin,
                                              unsigned* __restrict__ colmin) {
  __shared__ float4 sc[512];   // 8 KB
  int blk = blockIdx.x;
  int tid = threadIdx.x;

  if (blk < 512) {
    int qb = blk >> 3;           // [0,64)
    int seg = blk & 7;           // [0,8)
    int wb = qb >> 3;            // [0,8)
    int which = wb >> 2;         // 0=off, 1=up
    int b = wb & 3;
    int r0 = (qb & 7) * 1024 + tid * 4;   // [0,8192)
    {
      const float* gtb = gt + (size_t)b * NGG * 6 + (size_t)seg * 512 * 6;
      int i0 = tid * 2;
      const float4* g4 = (const float4*)(gtb + (size_t)i0 * 6);
      float4 u0 = g4[0], u1 = g4[1], u2 = g4[2];
      sc[i0] = make_float4(u0.x, u0.y, u0.z,
                           fmaf(u0.x, u0.x, fmaf(u0.y, u0.y, u0.z * u0.z)));
      sc[i0 + 1] = make_float4(u1.z, u1.w, u2.x,
                               fmaf(u1.z, u1.z, fmaf(u1.w, u1.w, u2.x * u2.x)));
    }
    const float* src = which ? up : off;
    const float4* s4 = (const float4*)src;
    size_t fb = ((size_t)(b * NUU + r0) * 3) >> 2;
    float4 A = s4[fb], B = s4[fb + 1], C = s4[fb + 2];
    float q0x = A.x, q0y = A.y, q0z = A.z;
    float q1x = A.w, q1y = B.x, q1z = B.y;
    float q2x = B.z, q2y = B.w, q2z = C.x;
    float q3x = C.y, q3y = C.z, q3z = C.w;
    float qq0 = fmaf(q0x, q0x, fmaf(q0y, q0y, q0z * q0z));
    float qq1 = fmaf(q1x, q1x, fmaf(q1y, q1y, q1z * q1z));
    float qq2 = fmaf(q2x, q2x, fmaf(q2y, q2y, q2z * q2z));
    float qq3 = fmaf(q3x, q3x, fmaf(q3y, q3y, q3z * q3z));
    float a0x = -2.f * q0x, a0y = -2.f * q0y, a0z = -2.f * q0z;
    float a1x = -2.f * q1x, a1y = -2.f * q1y, a1z = -2.f * q1z;
    float a2x = -2.f * q2x, a2y = -2.f * q2y, a2z = -2.f * q2z;
    float a3x = -2.f * q3x, a3y = -2.f * q3y, a3z = -2.f * q3z;
    __syncthreads();
    float b0 = 3.4e38f, b1 = 3.4e38f, b2 = 3.4e38f, b3 = 3.4e38f;
#pragma unroll 4
    for (int j = 0; j < 512; ++j) {
      float4 c = sc[j];
      float t;
      t = fmaf(c.x, a0x, c.w); t = fmaf(c.y, a0y, t); t = fmaf(c.z, a0z, t); b0 = fminf(b0, t);
      t = fmaf(c.x, a1x, c.w); t = fmaf(c.y, a1y, t); t = fmaf(c.z, a1z, t); b1 = fminf(b1, t);
      t = fmaf(c.x, a2x, c.w); t = fmaf(c.y, a2y, t); t = fmaf(c.z, a2z, t); b2 = fminf(b2, t);
      t = fmaf(c.x, a3x, c.w); t = fmaf(c.y, a3y, t); t = fmaf(c.z, a3z, t); b3 = fminf(b3, t);
    }
    int gr = which * 32768 + b * NUU + r0;
    atomicMin(&rowmin[gr + 0], fkey32(b0 + qq0));
    atomicMin(&rowmin[gr + 1], fkey32(b1 + qq1));
    atomicMin(&rowmin[gr + 2], fkey32(b2 + qq2));
    atomicMin(&rowmin[gr + 3], fkey32(b3 + qq3));

  } else if (blk < 1024) {
    int blk2 = blk - 512;
    int qb = blk2 >> 4;          // [0,32)
    int seg = blk2 & 15;         // [0,16)
    int which = qb >> 4;         // 0=off, 1=up
    int b = (qb >> 2) & 3;
    int m0 = (qb & 3) * 1024 + tid * 4;   // [0,4096)
    const float* src = which ? up : off;
    if (tid < 128) {
      const float* sb = src + (size_t)b * NUU * 3 + (size_t)seg * 512 * 3;
      int i0 = tid * 4;
      const float4* s4 = (const float4*)(sb + (size_t)i0 * 3);
      float4 u0 = s4[0], u1 = s4[1], u2 = s4[2];
      sc[i0] = make_float4(u0.x, u0.y, u0.z,
                           fmaf(u0.x, u0.x, fmaf(u0.y, u0.y, u0.z * u0.z)));
      sc[i0 + 1] = make_float4(u0.w, u1.x, u1.y,
                               fmaf(u0.w, u0.w, fmaf(u1.x, u1.x, u1.y * u1.y)));
      sc[i0 + 2] = make_float4(u1.z, u1.w, u2.x,
                               fmaf(u1.z, u1.z, fmaf(u1.w, u1.w, u2.x * u2.x)));
      sc[i0 + 3] = make_float4(u2.y, u2.z, u2.w,
                               fmaf(u2.y, u2.y, fmaf(u2.z, u2.z, u2.w * u2.w)));
    }
    const float* g = gt + (size_t)b * NGG * 6 + (size_t)m0 * 6;
    float q0x = g[0],  q0y = g[1],  q0z = g[2];
    float q1x = g[6],  q1y = g[7],  q1z = g[8];
    float q2x = g[12], q2y = g[13], q2z = g[14];
    float q3x = g[18], q3y = g[19], q3z = g[20];
    float qq0 = fmaf(q0x, q0x, fmaf(q0y, q0y, q0z * q0z));
    float qq1 = fmaf(q1x, q1x, fmaf(q1y, q1y, q1z * q1z));
    float qq2 = fmaf(q2x, q2x, fmaf(q2y, q2y, q2z * q2z));
    float qq3 = fmaf(q3x, q3x, fmaf(q3y, q3y, q3z * q3z));
    float a0x = -2.f * q0x, a0y = -2.f * q0y, a0z = -2.f * q0z;
    float a1x = -2.f * q1x, a1y = -2.f * q1y, a1z = -2.f * q1z;
    float a2x = -2.f * q2x, a2y = -2.f * q2y, a2z = -2.f * q2z;
    float a3x = -2.f * q3x, a3y = -2.f * q3y, a3z = -2.f * q3z;
    __syncthreads();
    float b0 = 3.4e38f, b1 = 3.4e38f, b2 = 3.4e38f, b3 = 3.4e38f;
#pragma unroll 4
    for (int j = 0; j < 512; ++j) {
      float4 c = sc[j];
      float t;
      t = fmaf(c.x, a0x, c.w); t = fmaf(c.y, a0y, t); t = fmaf(c.z, a0z, t); b0 = fminf(b0, t);
      t = fmaf(c.x, a1x, c.w); t = fmaf(c.y, a1y, t); t = fmaf(c.z, a1z, t); b1 = fminf(b1, t);
      t = fmaf(c.x, a2x, c.w); t = fmaf(c.y, a2y, t); t = fmaf(c.z, a2z, t); b2 = fminf(b2, t);
      t = fmaf(c.x, a3x, c.w); t = fmaf(c.y, a3y, t); t = fmaf(c.z, a3z, t); b3 = fminf(b3, t);
    }
    int gc = which * 16384 + b * NGG + m0;
    atomicMin(&colmin[gc + 0], fkey32(b0 + qq0));
    atomicMin(&colmin[gc + 1], fkey32(b1 + qq1));
    atomicMin(&colmin[gc + 2], fkey32(b2 + qq2));
    atomicMin(&colmin[gc + 3], fkey32(b3 + qq3));

  } else {
    int blk3 = blk - 1024;
    int qb = blk3 >> 4;          // [0,16)
    int seg = blk3 & 15;         // [0,16), 256 candidates each
    int b = qb >> 2;
    int m0 = (qb & 3) * 1024 + tid * 4;   // [0,4096)
    if (tid < 128) {
      const float* gtb = gt + (size_t)b * NGG * 6 + (size_t)seg * 256 * 6;
      int i0 = tid * 2;
      const float4* g4 = (const float4*)(gtb + (size_t)i0 * 6);
      float4 u0 = g4[0], u1 = g4[1], u2 = g4[2];
      sc[i0] = make_float4(u0.x, u0.y, u0.z,
                           fmaf(u0.x, u0.x, fmaf(u0.y, u0.y, u0.z * u0.z)));
      sc[i0 + 1] = make_float4(u1.z, u1.w, u2.x,
                               fmaf(u1.z, u1.z, fmaf(u1.w, u1.w, u2.x * u2.x)));
    }
    size_t fb = ((size_t)(b * NN + m0) * 3) >> 2;
    const float4* p4 = (const float4*)pts;
    float4 A = p4[fb], B = p4[fb + 1], C = p4[fb + 2];
    float q0x = A.x, q0y = A.y, q0z = A.z;
    float q1x = A.w, q1y = B.x, q1z = B.y;
    float q2x = B.z, q2y = B.w, q2z = C.x;
    float q3x = C.y, q3y = C.z, q3z = C.w;
    float a0x = -2.f * q0x, a0y = -2.f * q0y, a0z = -2.f * q0z;
    float a1x = -2.f * q1x, a1y = -2.f * q1y, a1z = -2.f * q1z;
    float a2x = -2.f * q2x, a2y = -2.f * q2y, a2z = -2.f * q2z;
    float a3x = -2.f * q3x, a3y = -2.f * q3y, a3z = -2.f * q3z;
    __syncthreads();
    float b0 = 3.4e38f, b1 = 3.4e38f, b2 = 3.4e38f, b3 = 3.4e38f;
    int i0 = 0, i1 = 0, i2 = 0, i3 = 0;
#pragma unroll 4
    for (int j = 0; j < 256; ++j) {
      float4 c = sc[j];
      float t; bool cc;
      t = fmaf(c.x, a0x, c.w); t = fmaf(c.y, a0y, t); t = fmaf(c.z, a0z, t);
      cc = t < b0; b0 = cc ? t : b0; i0 = cc ? j : i0;
      t = fmaf(c.x, a1x, c.w); t = fmaf(c.y, a1y, t); t = fmaf(c.z, a1z, t);
      cc = t < b1; b1 = cc ? t : b1; i1 = cc ? j : i1;
      t = fmaf(c.x, a2x, c.w); t = fmaf(c.y, a2y, t); t = fmaf(c.z, a2z, t);
      cc = t < b2; b2 = cc ? t : b2; i2 = cc ? j : i2;
      t = fmaf(c.x, a3x, c.w); t = fmaf(c.y, a3y, t); t = fmaf(c.z, a3z, t);
      cc = t < b3; b3 = cc ? t : b3; i3 = cc ? j : i3;
    }
    int q = b * NN + m0;
    int base = seg * 256;
    atomicMin(&keys[q + 0], ((unsigned long long)fkey32(b0) << 32) | (unsigned)(base + i0));
    atomicMin(&keys[q + 1], ((unsigned long long)fkey32(b1) << 32) | (unsigned)(base + i1));
    atomicMin(&keys[q + 2], ((unsigned long long)fkey32(b2) << 32) | (unsigned)(base + i2));
    atomicMin(&keys[q + 3], ((unsigned long long)fkey32(b3) << 32) | (unsigned)(base + i3));
  }
}

// ------------- fused: postgather (blocks 0..63) + reduce mins (64..447) -
__global__ __launch_bounds__(256) void k_post(
    const float* __restrict__ ori_pre, const float* __restrict__ nor_pre,
    const float* __restrict__ gt, const unsigned long long* __restrict__ keys,
    const unsigned* __restrict__ rowmin, const unsigned* __restrict__ colmin,
    float* __restrict__ nor_gt, float* __restrict__ ori_pro, float* __restrict__ acc) {
  __shared__ float sb1[4], sb2[4];
  int blk = blockIdx.x;
  if (blk < 64) {
    int q = blk * 256 + threadIdx.x;
    int b = q >> 12;
    float ox = ori_pre[q * 3 + 0], oy = ori_pre[q * 3 + 1], oz = ori_pre[q * 3 + 2];
    float n1 = sqrtf(fmaf(ox, ox, fmaf(oy, oy, oz * oz)) + 1e-8f) + 1e-10f;
    ox /= n1; oy /= n1; oz /= n1;
    float px = nor_pre[q * 3 + 0], py = nor_pre[q * 3 + 1], pz = nor_pre[q * 3 + 2];
    float n2 = sqrtf(fmaf(px, px, fmaf(py, py, pz * pz)) + 1e-8f) + 1e-10f;
    px /= n2; py /= n2; pz /= n2;
    unsigned idx = (unsigned)(keys[q] & 0xffffffffULL);
    const float* g = gt + (size_t)b * NGG * 6 + (size_t)idx * 6 + 3;
    float gx = g[0], gy = g[1], gz = g[2];
    float dn = fmaf(gx, ox, fmaf(gy, oy, gz * oz));
    float vx = ox - gx * dn, vy = oy - gy * dn, vz = oz - gz * dn;
    float n3 = sqrtf(fmaf(vx, vx, fmaf(vy, vy, vz * vz)) + 1e-8f) + 1e-10f;
    vx /= n3; vy /= n3; vz /= n3;
    nor_gt[q * 3 + 0] = gx; nor_gt[q * 3 + 1] = gy; nor_gt[q * 3 + 2] = gz;
    ori_pro[q * 3 + 0] = vx; ori_pro[q * 3 + 1] = vy; ori_pro[q * 3 + 2] = vz;
    float na = fmaxf(sqrtf(fmaf(gx, gx, fmaf(gy, gy, gz * gz))), 1e-8f);
    float nb = fmaxf(sqrtf(fmaf(px, px, fmaf(py, py, pz * pz))), 1e-8f);
    float cs = fmaf(gx, px, fmaf(gy, py, gz * pz)) / (na * nb);
    float t_nor = 1.f - fabsf(cs);
    float t_ori = fabsf(dn);
    float s1 = block_sum_256(t_nor, sb1);
    float s2 = block_sum_256(t_ori, sb2);
    if (threadIdx.x == 0) {
      atomicAdd(&acc[1], s1);
      atomicAdd(&acc[2], s2);
    }
  } else {
    int rblk = blk - 64;   // [0,384)
    float v;
    int slot;
    if (rblk < 256) {
      int i = rblk * 256 + threadIdx.x;
      v = unfkey32(rowmin[i]);
      slot = (i >> 15) ? 5 : 3;
    } else {
      int i = (rblk - 256) * 256 + threadIdx.x;
      v = unfkey32(colmin[i]);
      slot = (i >> 14) ? 6 : 4;
    }
    float s = block_sum_256(v, sb1);
    if (threadIdx.x == 0) atomicAdd(&acc[slot], s);
  }
}

// ------------- KNN (K=6) among pts + fused loss_smooth -----------------
// grid (512): 32 queries/block, 8 threads/query, interleaved candidates.
// R3-proven single insert mechanism; loop split at j=128 with a t6 gate:
// after 128 iters (1024 cands/query) t6 = shfl-min of the 8 lanes' 6th-best
// is a rigorous upper bound on the query's true 6th-NN distance, so the
// remaining 384 iters skip candidates with d > t6 exactly (>=6 smaller keys
// already exist; skipped candidates can never win the merge).
__global__ __launch_bounds__(256) void k_knn_smooth(const float* __restrict__ pts,
                                                    const float* __restrict__ nor_gt,
                                                    const float* __restrict__ ori_pro,
                                                    float* __restrict__ acc) {
  __shared__ float4 sp[4096];                             // 64 KB
  __shared__ unsigned long long marr[32 * 48];            // 12 KB
  __shared__ float sbuf[4];
  int q_local = threadIdx.x >> 3;
  int t = threadIdx.x & 7;
  int q = blockIdx.x * 32 + q_local;
  int b = q >> 12;
  int n = q & 4095;
  const float* pb = pts + (size_t)b * NN * 3;
  for (int p = threadIdx.x; p < 4096; p += 256) {
    float x = pb[p * 3 + 0], y = pb[p * 3 + 1], z = pb[p * 3 + 2];
    sp[p] = make_float4(x, y, z, fmaf(x, x, fmaf(y, y, z * z)));
  }
  __syncthreads();
  float4 qp = sp[n];
  float qx2 = -2.f * qp.x, qy2 = -2.f * qp.y, qz2 = -2.f * qp.z;
  float d0 = 3.4e38f, d1 = 3.4e38f, d2 = 3.4e38f,
        d3 = 3.4e38f, d4 = 3.4e38f, d5 = 3.4e38f;
  int i0 = 0, i1 = 0, i2 = 0, i3 = 0, i4 = 0, i5 = 0;
  // ---- phase A: first 128 iters (candidates c < 1024), R3 body ----
#pragma unroll 4
  for (int j = 0; j < 128; ++j) {
    int c = (j << 3) | t;    // interleaved: 8-lane-contiguous + broadcast
    float4 p = sp[c];
    float d = fmaf(p.x, qx2, p.w);
    d = fmaf(p.y, qy2, d);
    d = fmaf(p.z, qz2, d);
    if (d < d5) {            // sorted insertion of (d, c)
      int ci = c;
      bool cc; float nd; int ni;
      cc = d < d0; nd = cc ? d : d0; d = cc ? d0 : d; ni = cc ? ci : i0; ci = cc ? i0 : ci; d0 = nd; i0 = ni;
      cc = d < d1; nd = cc ? d : d1; d = cc ? d1 : d; ni = cc ? ci : i1; ci = cc ? i1 : ci; d1 = nd; i1 = ni;
      cc = d < d2; nd = cc ? d : d2; d = cc ? d2 : d; ni = cc ? ci : i2; ci = cc ? i2 : ci; d2 = nd; i2 = ni;
      cc = d < d3; nd = cc ? d : d3; d = cc ? d3 : d; ni = cc ? ci : i3; ci = cc ? i3 : ci; d3 = nd; i3 = ni;
      cc = d < d4; nd = cc ? d : d4; d = cc ? d4 : d; ni = cc ? ci : i4; ci = cc ? i4 : ci; d4 = nd; i4 = ni;
      cc = d < d5; nd = cc ? d : d5;                    ni = cc ? ci : i5;                  d5 = nd; i5 = ni;
    }
  }
  // rigorous 6th-NN upper bound for this query
  float t6 = d5;
  t6 = fminf(t6, __shfl_xor(t6, 1, 64));
  t6 = fminf(t6, __shfl_xor(t6, 2, 64));
  t6 = fminf(t6, __shfl_xor(t6, 4, 64));
  // ---- phase B: remaining 384 iters, gated on d <= t6 (rare) ----
#pragma unroll 4
  for (int j = 128; j < 512; ++j) {
    int c = (j << 3) | t;
    float4 p = sp[c];
    float d = fmaf(p.x, qx2, p.w);
    d = fmaf(p.y, qy2, d);
    d = fmaf(p.z, qz2, d);
    if (d <= t6) {
      int ci = c;
      bool cc; float nd; int ni;
      cc = d < d0; nd = cc ? d : d0; d = cc ? d0 : d; ni = cc ? ci : i0; ci = cc ? i0 : ci; d0 = nd; i0 = ni;
      cc = d < d1; nd = cc ? d : d1; d = cc ? d1 : d; ni = cc ? ci : i1; ci = cc ? i1 : ci; d1 = nd; i1 = ni;
      cc = d < d2; nd = cc ? d : d2; d = cc ? d2 : d; ni = cc ? ci : i2; ci = cc ? i2 : ci; d2 = nd; i2 = ni;
      cc = d < d3; nd = cc ? d : d3; d = cc ? d3 : d; ni = cc ? ci : i3; ci = cc ? i3 : ci; d3 = nd; i3 = ni;
      cc = d < d4; nd = cc ? d : d4; d = cc ? d4 : d; ni = cc ? ci : i4; ci = cc ? i4 : ci; d4 = nd; i4 = ni;
      cc = d < d5; nd = cc ? d : d5;                    ni = cc ? ci : i5;                  d5 = nd; i5 = ni;
    }
  }
  unsigned long long* mq = &marr[q_local * 48 + t * 6];
  // fkey32 REQUIRED: d' can be negative; raw float bits mis-order in u64.
  mq[0] = ((unsigned long long)fkey32(d0) << 32) | (unsigned)i0;
  mq[1] = ((unsigned long long)fkey32(d1) << 32) | (unsigned)i1;
  mq[2] = ((unsigned long long)fkey32(d2) << 32) | (unsigned)i2;
  mq[3] = ((unsigned long long)fkey32(d3) << 32) | (unsigned)i3;
  mq[4] = ((unsigned long long)fkey32(d4) << 32) | (unsigned)i4;
  mq[5] = ((unsigned long long)fkey32(d5) << 32) | (unsigned)i5;
  __syncthreads();
  float sum = 0.f;
  if (t == 0) {
    float ngx = nor_gt[q * 3 + 0], ngy = nor_gt[q * 3 + 1], ngz = nor_gt[q * 3 + 2];
    float box = ori_pro[q * 3 + 0], boy = ori_pro[q * 3 + 1], boz = ori_pro[q * 3 + 2];
    float rx = boy * ngz - boz * ngy;
    float ry = boz * ngx - box * ngz;
    float rz = box * ngy - boy * ngx;
    float nbo = fmaxf(sqrtf(fmaf(box, box, fmaf(boy, boy, boz * boz))), 1e-8f);
    float nrot = fmaxf(sqrtf(fmaf(rx, rx, fmaf(ry, ry, rz * rz))), 1e-8f);
    const unsigned long long* mrow = &marr[q_local * 48];
    int head[8] = {0, 0, 0, 0, 0, 0, 0, 0};
    for (int k = 0; k < 6; ++k) {
      unsigned long long best = ~0ULL;
      int bl = 0;
#pragma unroll
      for (int l = 0; l < 8; ++l) {
        unsigned long long v = mrow[l * 6 + head[l]];
        if (v < best) { best = v; bl = l; }
      }
#pragma unroll
      for (int l = 0; l < 8; ++l) head[l] += (l == bl) ? 1 : 0;
      int id = (int)(best & 0xffffffffULL);
      const float* gn = &nor_gt[(size_t)(b * 4096 + id) * 3];
      const float* go = &ori_pro[(size_t)(b * 4096 + id) * 3];
      float gnx = gn[0], gny = gn[1], gnz = gn[2];
      float gox = go[0], goy = go[1], goz = go[2];
      float nd = fmaf(gnx, ngx, fmaf(gny, ngy, gnz * ngz));
      float wv = (expf(-nd / 0.3f) * 10.f + 1.f) < 4.f ? 1.f : 5.f;
      float ngo = fmaxf(sqrtf(fmaf(gox, gox, fmaf(goy, goy, goz * goz))), 1e-8f);
      float c0 = fmaf(gox, box, fmaf(goy, boy, goz * boz)) / (ngo * nbo);
      float c1 = fmaf(gox, rx, fmaf(goy, ry, goz * rz)) / (ngo * nrot);
      float cosv = fminf(1.f - fabsf(c0), 1.f - fabsf(c1));
      sum += wv * cosv;
    }
  }
  float s = block_sum_256(sum, sbuf);
  if (threadIdx.x == 0) atomicAdd(&acc[0], s);
}

// ------------- combine to the 7 outputs --------------------------------
__global__ void k_finalize(const float* __restrict__ acc, float* __restrict__ out) {
  if (threadIdx.x == 0 && blockIdx.x == 0) {
    float loss_smooth = acc[0] / 98304.f;            // B*N*K
    float loss_nor = acc[1] / 16384.f;               // B*N
    float loss_nor_ori = acc[2] / 16384.f;
    float lco = acc[3] / 32768.f + acc[4] / 16384.f; // B*NU rows + B*NG cols
    float lc = acc[5] / 32768.f + acc[6] / 16384.f;
    float loss_cd = lc + 0.4f * lco;
    float loss = loss_smooth + loss_nor + 0.1f * loss_nor_ori + 200.f * loss_cd;
    out[0] = loss;
    out[1] = loss_smooth;
    out[2] = loss_nor;
    out[3] = lco;
    out[4] = loss_nor_ori;
    out[5] = lc;
    out[6] = lc;
  }
}

extern "C" void kernel_launch(void* const* d_in, const int* in_sizes, int n_in,
                              void* d_out, int out_size, void* d_ws, size_t ws_size,
                              hipStream_t stream) {
  (void)in_sizes; (void)n_in; (void)out_size; (void)ws_size;
  const float* ori_pre = (const float*)d_in[0];
  const float* nor_pre = (const float*)d_in[1];
  const float* xyz_up = (const float*)d_in[2];
  const float* xyz_off = (const float*)d_in[3];
  const float* pts = (const float*)d_in[4];
  const float* gt = (const float*)d_in[5];
  float* out = (float*)d_out;
  char* ws = (char*)d_ws;

  float* acc = (float*)(ws + 0);                                   // 16 floats
  unsigned long long* keys = (unsigned long long*)(ws + 512);      // 16384 u64 = 128 KB
  unsigned* rowmin = (unsigned*)(ws + 512 + 131072);               // 65536 u32 = 256 KB
  unsigned* colmin = (unsigned*)(ws + 512 + 131072 + 262144);      // 32768 u32 = 128 KB
  float* nor_gt = (float*)(ws + 512 + 131072 + 262144 + 131072);   // 49152 f32 = 192 KB
  float* ori_pro = (float*)(ws + 512 + 131072 + 262144 + 131072 + 196608);

  hipMemsetAsync(acc, 0, 64, stream);
  hipMemsetAsync(ws + 512, 0xFF, 131072 + 262144 + 131072, stream);

  k_scan<<<1280, 256, 0, stream>>>(pts, gt, xyz_up, xyz_off, keys, rowmin, colmin);
  k_post<<<448, 256, 0, stream>>>(ori_pre, nor_pre, gt, keys, rowmin, colmin,
                                  nor_gt, ori_pro, acc);
  k_knn_smooth<<<512, 256, 0, stream>>>(pts, nor_gt, ori_pro, acc);
  k_finalize<<<1, 64, 0, stream>>>(acc, out);
}